// Round 7
// baseline (644.866 us; speedup 1.0000x reference)
//
#include <hip/hip_runtime.h>

// SNN forward. conv2 + fc1 on MFMA bf16, 3-way weight splits (hi+lo+lolo).
// R7: LDS bank-conflict fix — B-tile cg-row stride padded 144->146 shorts
//     (odd dword stride => lane bank (9q+4xl) mod 32, 2 lanes/bank = free);
//     fc1 sB stride 40->42. Structure otherwise identical to R6.

#define LIF_STEP(vv, xx, ss) do { \
    vv = fmaf((xx) - vv, 0.5f, vv); \
    ss = (vv >= 1.0f) ? 1.0f : 0.0f; \
    vv = (vv >= 1.0f) ? 0.0f : vv; \
  } while (0)

typedef __attribute__((ext_vector_type(8))) short short8;
typedef __attribute__((ext_vector_type(4))) float f32x4;

__device__ __forceinline__ float bf2f(unsigned short u) {
  return __uint_as_float(((unsigned)u) << 16);
}
__device__ __forceinline__ unsigned short f2bf(float f) {
  return (unsigned short)(__float_as_uint(f) >> 16);  // exact for k/4 spike values
}

// ---- workspace layout (float-slot offsets) ----
// pool1 bf16 [1024 tb][8 cg][16 py][16 px][8 ci_l] = 16,777,216 u16
//   (region reused AFTER conv2 as fc1 partials f32 [16 kb][256 o][1024 tb])
// pool2 bf16 [1024 tb][64 s][128 ci]               =  8,388,608 u16
#define OFF_POOL1   0u
#define OFF_POOL2   8388608u
#define OFF_STATS   12582912u   // f32 16,896
#define OFF_FC1S    12599808u   // f32 262,144
#define OFF_A2      12861952u   // bf16 3x[18 kc][128 co][4 q][8 j]
#define OFF_B1      12972544u   // bf16 3x[256 kc][256 o][4 q][8 j]
// total 16,118,272 floats = 64.5 MB
// stats sublayout: s1_sum(64) s1_sq(64) bn1_sc(64) bn1_sh(64)
//                  bn2_sc(128) bn2_sh(128) s2_part[64 sp][2][128]
#define STATS_N 16896u

// padded LDS B-tile geometry for conv2 kernels
#define CGROW 146              // shorts per [cg]-row (144 used + 2 pad) == 73 dwords (odd)
#define ROWSTRIDE (8 * CGROW)  // 1168 shorts per image row

__global__ __launch_bounds__(256) void zero_kernel(float* __restrict__ p, unsigned n) {
  unsigned i = blockIdx.x * 256u + threadIdx.x;
  if (i < n) p[i] = 0.0f;
}

// conv2_w [co 128][ci 64][dy 3][dx 3] fp32 -> 3-way bf16 split in MFMA A-frag order
__global__ __launch_bounds__(256) void prep_w2(const float* __restrict__ w, unsigned short* __restrict__ A2) {
  int i = blockIdx.x * 256 + threadIdx.x;
  if (i >= 73728) return;
  int co = i / 576, r = i - co * 576;
  int ci = r / 9, t9 = r - ci * 9;
  int k = t9 * 64 + ci;
  int kc = k >> 5, q = (k >> 3) & 3, j = k & 7;
  int off = ((kc * 128 + co) * 4 + q) * 8 + j;
  float wv = w[i];
  unsigned short hi = f2bf(wv);
  float rem = wv - bf2f(hi);
  unsigned short lo = f2bf(rem);
  float rem2 = rem - bf2f(lo);
  A2[off] = hi;
  A2[73728 + off] = lo;
  A2[147456 + off] = f2bf(rem2);
}

// fc1_w -> 3-way split, coalesced writes; permuted k = s*128+ci (pool2 is [s][ci]).
__global__ __launch_bounds__(256) void prep_b1(const float* __restrict__ w, unsigned short* __restrict__ B1) {
  int i = blockIdx.x * 256 + threadIdx.x;   // 2,097,152 total
  int j = i & 7, q = (i >> 3) & 3, o = (i >> 5) & 255, kc = i >> 13;
  int k = kc * 32 + q * 8 + j;
  int ci = k & 127, s = k >> 7;
  float wv = w[o * 8192 + ci * 64 + s];
  unsigned short hi = f2bf(wv);
  float rem = wv - bf2f(hi);
  unsigned short lo = f2bf(rem);
  float rem2 = rem - bf2f(lo);
  B1[i] = hi;
  B1[2097152 + i] = lo;
  B1[4194304 + i] = f2bf(rem2);
}

// ---- conv1 pass 1: stats only. (validated) ----
__global__ __launch_bounds__(256) void conv1_pass1(const float* __restrict__ x,
                                                   const float* __restrict__ w,
                                                   float* __restrict__ s_sum,
                                                   float* __restrict__ s_sq) {
  int tb = blockIdx.x;
  __shared__ float simg[3 * 32 * 36];
  int tid = threadIdx.x;
  const float* xb = x + tb * 3072;
  for (int i = tid; i < 3456; i += 256) {
    int ci = i / 1152, rem = i - ci * 1152;
    int y = rem / 36, px = rem - y * 36;
    int gx = px - 1;
    simg[i] = ((unsigned)gx < 32u) ? xb[(ci * 32 + y) * 32 + gx] : 0.0f;
  }
  __syncthreads();

  int cgrp = tid >> 3, rowthr = tid & 7;
  int c0 = cgrp * 2;
  float w0[27], w1[27];
#pragma unroll
  for (int j = 0; j < 27; ++j) { w0[j] = w[c0 * 27 + j]; w1[j] = w[c0 * 27 + 27 + j]; }

  float s1a = 0.f, s2a = 0.f, s1b = 0.f, s2b = 0.f;
  for (int task = 0; task < 8; ++task) {
    int y = rowthr + (task & 3) * 8;
    int x0 = (task >> 2) * 16;
    float acc0[16] = {0.f,0.f,0.f,0.f,0.f,0.f,0.f,0.f,0.f,0.f,0.f,0.f,0.f,0.f,0.f,0.f};
    float acc1[16] = {0.f,0.f,0.f,0.f,0.f,0.f,0.f,0.f,0.f,0.f,0.f,0.f,0.f,0.f,0.f,0.f};
#pragma unroll
    for (int ci = 0; ci < 3; ++ci) {
#pragma unroll
      for (int dy = 0; dy < 3; ++dy) {
        int yy = y + dy - 1;
        if (yy >= 0 && yy < 32) {
          const float* row = simg + (ci * 32 + yy) * 36 + x0;
          float rr[20];
#pragma unroll
          for (int q = 0; q < 5; ++q) {
            float4 f = *(const float4*)(row + q * 4);
            rr[q*4+0] = f.x; rr[q*4+1] = f.y; rr[q*4+2] = f.z; rr[q*4+3] = f.w;
          }
#pragma unroll
          for (int dx = 0; dx < 3; ++dx) {
            float wa = w0[ci*9 + dy*3 + dx], wb = w1[ci*9 + dy*3 + dx];
#pragma unroll
            for (int xi = 0; xi < 16; ++xi) {
              float v = rr[xi + dx];
              acc0[xi] = fmaf(wa, v, acc0[xi]);
              acc1[xi] = fmaf(wb, v, acc1[xi]);
            }
          }
        }
      }
    }
#pragma unroll
    for (int xi = 0; xi < 16; ++xi) {
      s1a += acc0[xi]; s2a = fmaf(acc0[xi], acc0[xi], s2a);
      s1b += acc1[xi]; s2b = fmaf(acc1[xi], acc1[xi], s2b);
    }
  }
#pragma unroll
  for (int off = 1; off < 8; off <<= 1) {
    s1a += __shfl_xor(s1a, off); s2a += __shfl_xor(s2a, off);
    s1b += __shfl_xor(s1b, off); s2b += __shfl_xor(s2b, off);
  }
  if (rowthr == 0) {
    atomicAdd(&s_sum[c0], s1a);     atomicAdd(&s_sq[c0], s2a);
    atomicAdd(&s_sum[c0 + 1], s1b); atomicAdd(&s_sq[c0 + 1], s2b);
  }
}

__global__ void finalize_bn(const float* __restrict__ sum, const float* __restrict__ sq,
                            const float* __restrict__ g, const float* __restrict__ b,
                            float* __restrict__ scale, float* __restrict__ shift, float inv_n) {
  int c = threadIdx.x;
  float mean = sum[c] * inv_n;
  float var = fmaxf(sq[c] * inv_n - mean * mean, 0.0f);
  float rstd = rsqrtf(var + 1e-5f);
  float sc = g[c] * rstd;
  scale[c] = sc;
  shift[c] = fmaf(-mean, sc, b[c]);
}

// layer-2 finalize: reduce 64-way spread partials [sp][2][128]
__global__ void finalize_bn2(const float* __restrict__ s2p,
                             const float* __restrict__ g, const float* __restrict__ b,
                             float* __restrict__ scale, float* __restrict__ shift, float inv_n) {
  int c = threadIdx.x;   // 128
  float s1 = 0.f, s2 = 0.f;
#pragma unroll 8
  for (int sp = 0; sp < 64; ++sp) {
    s1 += s2p[sp * 256 + c];
    s2 += s2p[sp * 256 + 128 + c];
  }
  float mean = s1 * inv_n;
  float var = fmaxf(s2 * inv_n - mean * mean, 0.0f);
  float rstd = rsqrtf(var + 1e-5f);
  float sc = g[c] * rstd;
  scale[c] = sc;
  shift[c] = fmaf(-mean, sc, b[c]);
}

// ---- conv1 pass 2: fused conv+BN+LIF+pool -> pool1 [tb][cg][py][px][ci_l 8]. (validated) ----
__global__ __launch_bounds__(256) void conv1_fused(const float* __restrict__ x,
    const float* __restrict__ w, const float* __restrict__ scale, const float* __restrict__ shift,
    unsigned short* __restrict__ pool1) {
  int b = blockIdx.x >> 3, cg = blockIdx.x & 7;
  int tid = threadIdx.x;
  int co_l = tid >> 5;
  int co = cg * 8 + co_l;
  int y = tid & 31;
  __shared__ float simg[3 * 34 * 36];
  __shared__ unsigned short shp[2112];
  float wreg[27];
#pragma unroll
  for (int j = 0; j < 27; ++j) wreg[j] = w[co * 27 + j];
  float sc = scale[co], sh = shift[co];
  float v[32];
#pragma unroll
  for (int i = 0; i < 32; ++i) v[i] = 0.f;

  for (int t = 0; t < 8; ++t) {
    int tb = t * 128 + b;
    const float* xb = x + tb * 3072;
    __syncthreads();
    for (int i = tid; i < 3672; i += 256) {
      int ci = i / 1224, r = i - ci * 1224;
      int yy = r / 36, xx = r - yy * 36;
      int gy = yy - 1, gx = xx - 1;
      simg[i] = ((unsigned)gy < 32u && (unsigned)gx < 32u) ? xb[(ci * 32 + gy) * 32 + gx] : 0.f;
    }
    __syncthreads();
    float acc[32];
#pragma unroll
    for (int i = 0; i < 32; ++i) acc[i] = 0.f;
#pragma unroll
    for (int ci = 0; ci < 3; ++ci) {
#pragma unroll
      for (int dy = 0; dy < 3; ++dy) {
        const float* row = simg + (ci * 34 + y + dy) * 36;
        float rr[36];
#pragma unroll
        for (int q = 0; q < 9; ++q) {
          float4 f = *(const float4*)(row + q * 4);
          rr[q*4+0]=f.x; rr[q*4+1]=f.y; rr[q*4+2]=f.z; rr[q*4+3]=f.w;
        }
#pragma unroll
        for (int dx = 0; dx < 3; ++dx) {
          float wv = wreg[ci * 9 + dy * 3 + dx];
#pragma unroll
          for (int xx2 = 0; xx2 < 32; ++xx2)
            acc[xx2] = fmaf(wv, rr[xx2 + dx], acc[xx2]);
        }
      }
    }
    float hp[16];
#pragma unroll
    for (int px = 0; px < 16; ++px) {
      float s0, s1, xv;
      xv = fmaf(acc[2*px],   sc, sh); LIF_STEP(v[2*px],   xv, s0);
      xv = fmaf(acc[2*px+1], sc, sh); LIF_STEP(v[2*px+1], xv, s1);
      hp[px] = s0 + s1;
    }
    unsigned short ob[16];
#pragma unroll
    for (int px = 0; px < 16; ++px) {
      float sum = hp[px] + __shfl_xor(hp[px], 1);
      ob[px] = f2bf(0.25f * sum);
    }
    if ((y & 1) == 0) {
      int py = y >> 1;
#pragma unroll
      for (int px = 0; px < 16; ++px)
        shp[py * 132 + px * 8 + co_l] = ob[px];
    }
    __syncthreads();
    {
      int o = (tid >> 4) * 132 + (tid & 15) * 8;
      uint2 lo = *(const uint2*)&shp[o];
      uint2 hi = *(const uint2*)&shp[o + 4];
      *(uint4*)(pool1 + (size_t)tb * 16384 + cg * 2048 + tid * 8) = make_uint4(lo.x, lo.y, hi.x, hi.y);
    }
  }
}

// ---- conv2 pass 1 (MFMA): stats only. Block = (tb, row-quarter); padded LDS. ----
__global__ __launch_bounds__(256, 2) void conv2_pass1_mfma(const unsigned short* __restrict__ pool1,
    const unsigned short* __restrict__ A2, float* __restrict__ s2p) {
  int bx = blockIdx.x;
  int tb = bx >> 2, q4 = bx & 3;
  int sp = bx & 63;
  __shared__ unsigned short simg[6 * ROWSTRIDE];   // 14,016 B : [row 6][cg 8][146]
  int tid = threadIdx.x;
  const unsigned* src = (const unsigned*)(pool1 + (size_t)tb * 16384);
  unsigned* dstw = (unsigned*)simg;
  // 6 rows x 8 cg x 73 dwords (72 used + 1 pad)
  for (int i = tid; i < 3504; i += 256) {
    int jj = i / 73, r = i - jj * 73;      // jj = row*8+cg
    int cg = jj & 7, row_l = jj >> 3;
    unsigned val = 0u;
    if (r < 72) {
      int xx = r >> 2, cp = r & 3;
      int yi = q4 * 4 - 1 + row_l, gx = xx - 1;
      if ((unsigned)yi < 16u && (unsigned)gx < 16u)
        val = src[cg * 1024 + yi * 64 + gx * 4 + cp];
    }
    dstw[i] = val;
  }
  __syncthreads();

  int wave = tid >> 6, lane = tid & 63;
  int xl = lane & 15, q = lane >> 4;
  int m0 = wave * 32;
  f32x4 acc[2][4];
#pragma unroll
  for (int mt = 0; mt < 2; ++mt)
#pragma unroll
    for (int yl = 0; yl < 4; ++yl) acc[mt][yl] = (f32x4){0.f, 0.f, 0.f, 0.f};

  short8 a_cur[2][3];
#pragma unroll
  for (int mt = 0; mt < 2; ++mt) {
    int aoff = ((m0 + mt * 16 + xl) * 4 + q) * 8;
    a_cur[mt][0] = *(const short8*)(A2 + aoff);
    a_cur[mt][1] = *(const short8*)(A2 + 73728 + aoff);
    a_cur[mt][2] = *(const short8*)(A2 + 147456 + aoff);
  }

#pragma unroll 1
  for (int kc = 0; kc < 18; ++kc) {
    short8 a_nxt[2][3];
    if (kc < 17) {
#pragma unroll
      for (int mt = 0; mt < 2; ++mt) {
        int aoff = (((kc + 1) * 128 + m0 + mt * 16 + xl) * 4 + q) * 8;
        a_nxt[mt][0] = *(const short8*)(A2 + aoff);
        a_nxt[mt][1] = *(const short8*)(A2 + 73728 + aoff);
        a_nxt[mt][2] = *(const short8*)(A2 + 147456 + aoff);
      }
    } else {
#pragma unroll
      for (int mt = 0; mt < 2; ++mt)
#pragma unroll
        for (int sv = 0; sv < 3; ++sv) a_nxt[mt][sv] = a_cur[mt][sv];
    }
    int tap = kc >> 1;
    int dy = tap / 3, dx = tap - dy * 3;
    int cgq = (kc & 1) * 4 + q;
#pragma unroll
    for (int yl = 0; yl < 4; ++yl) {
      int baddr = ((yl + dy) * 8 + cgq) * CGROW + (xl + dx) * 8;
      short8 bb = *(const short8*)(simg + baddr);
#pragma unroll
      for (int mt = 0; mt < 2; ++mt) {
        acc[mt][yl] = __builtin_amdgcn_mfma_f32_16x16x32_bf16(a_cur[mt][0], bb, acc[mt][yl], 0, 0, 0);
        acc[mt][yl] = __builtin_amdgcn_mfma_f32_16x16x32_bf16(a_cur[mt][1], bb, acc[mt][yl], 0, 0, 0);
        acc[mt][yl] = __builtin_amdgcn_mfma_f32_16x16x32_bf16(a_cur[mt][2], bb, acc[mt][yl], 0, 0, 0);
      }
    }
#pragma unroll
    for (int mt = 0; mt < 2; ++mt)
#pragma unroll
      for (int sv = 0; sv < 3; ++sv) a_cur[mt][sv] = a_nxt[mt][sv];
  }
#pragma unroll
  for (int mt = 0; mt < 2; ++mt)
#pragma unroll
    for (int reg = 0; reg < 4; ++reg) {
      float s1 = 0.f, s2 = 0.f;
#pragma unroll
      for (int yl = 0; yl < 4; ++yl) {
        float val = acc[mt][yl][reg];
        s1 += val; s2 = fmaf(val, val, s2);
      }
#pragma unroll
      for (int off = 1; off < 16; off <<= 1) {
        s1 += __shfl_xor(s1, off); s2 += __shfl_xor(s2, off);
      }
      if (xl == 0) {
        int co = m0 + mt * 16 + q * 4 + reg;
        atomicAdd(&s2p[sp * 256 + co], s1);
        atomicAdd(&s2p[sp * 256 + 128 + co], s2);
      }
    }
}

// ---- conv2 pass 2 (MFMA): fused conv+BN+LIF+pool. Block = (b, row-pair); padded LDS. ----
__global__ __launch_bounds__(256, 2) void conv2_fused_mfma(const unsigned short* __restrict__ pool1,
    const unsigned short* __restrict__ A2,
    const float* __restrict__ scale, const float* __restrict__ shift,
    unsigned short* __restrict__ pool2) {
  int b = blockIdx.x >> 3, q8 = blockIdx.x & 7;
  __shared__ unsigned short simg[2 * 4 * ROWSTRIDE];   // 18,688 B : [t_l][row 4][cg 8][146]
  __shared__ unsigned short shout[2 * 8 * 136];        // 4,352 B
  int tid = threadIdx.x, wave = tid >> 6, lane = tid & 63;
  int xl = lane & 15, q = lane >> 4;
  int m0 = wave * 32;

  float scr[2][4], shr[2][4];
#pragma unroll
  for (int mt = 0; mt < 2; ++mt)
#pragma unroll
    for (int reg = 0; reg < 4; ++reg) {
      int co = m0 + mt * 16 + q * 4 + reg;
      scr[mt][reg] = scale[co]; shr[mt][reg] = shift[co];
    }
  float v[2][2][4];
#pragma unroll
  for (int mt = 0; mt < 2; ++mt)
#pragma unroll
    for (int yl = 0; yl < 2; ++yl)
#pragma unroll
      for (int reg = 0; reg < 4; ++reg) v[mt][yl][reg] = 0.f;

#pragma unroll 1
  for (int tg = 0; tg < 4; ++tg) {
    __syncthreads();
    // stage rows 2*q8-1 .. 2*q8+2 of images (tg*2, tg*2+1); 2 x 4 x 8 x 73 dwords
    for (int i = tid; i < 4672; i += 256) {
      int t_l = (i >= 2336) ? 1 : 0;
      int r0 = i - t_l * 2336;
      int jj = r0 / 73, r = r0 - jj * 73;
      int cg = jj & 7, row_l = jj >> 3;
      unsigned val = 0u;
      if (r < 72) {
        int xx = r >> 2, cp = r & 3;
        int yi = q8 * 2 - 1 + row_l, gx = xx - 1;
        if ((unsigned)yi < 16u && (unsigned)gx < 16u)
          val = ((const unsigned*)pool1)[(size_t)((tg * 2 + t_l) * 128 + b) * 8192 + cg * 1024 + yi * 64 + gx * 4 + cp];
      }
      ((unsigned*)simg)[i] = val;
    }
    __syncthreads();

    f32x4 acc[2][2][2];   // [t_l][mt][yl]
#pragma unroll
    for (int t_l = 0; t_l < 2; ++t_l)
#pragma unroll
      for (int mt = 0; mt < 2; ++mt)
#pragma unroll
        for (int yl = 0; yl < 2; ++yl) acc[t_l][mt][yl] = (f32x4){0.f, 0.f, 0.f, 0.f};

    short8 a_cur[2][3];
#pragma unroll
    for (int mt = 0; mt < 2; ++mt) {
      int aoff = ((m0 + mt * 16 + xl) * 4 + q) * 8;
      a_cur[mt][0] = *(const short8*)(A2 + aoff);
      a_cur[mt][1] = *(const short8*)(A2 + 73728 + aoff);
      a_cur[mt][2] = *(const short8*)(A2 + 147456 + aoff);
    }

#pragma unroll 1
    for (int kc = 0; kc < 18; ++kc) {
      short8 a_nxt[2][3];
      if (kc < 17) {
#pragma unroll
        for (int mt = 0; mt < 2; ++mt) {
          int aoff = (((kc + 1) * 128 + m0 + mt * 16 + xl) * 4 + q) * 8;
          a_nxt[mt][0] = *(const short8*)(A2 + aoff);
          a_nxt[mt][1] = *(const short8*)(A2 + 73728 + aoff);
          a_nxt[mt][2] = *(const short8*)(A2 + 147456 + aoff);
        }
      } else {
#pragma unroll
        for (int mt = 0; mt < 2; ++mt)
#pragma unroll
          for (int sv = 0; sv < 3; ++sv) a_nxt[mt][sv] = a_cur[mt][sv];
      }
      int tap = kc >> 1;
      int dy = tap / 3, dx = tap - dy * 3;
      int cgq = (kc & 1) * 4 + q;
#pragma unroll
      for (int t_l = 0; t_l < 2; ++t_l) {
#pragma unroll
        for (int yl = 0; yl < 2; ++yl) {
          int baddr = t_l * 4672 + ((yl + dy) * 8 + cgq) * CGROW + (xl + dx) * 8;
          short8 bb = *(const short8*)(simg + baddr);
#pragma unroll
          for (int mt = 0; mt < 2; ++mt) {
            acc[t_l][mt][yl] = __builtin_amdgcn_mfma_f32_16x16x32_bf16(a_cur[mt][0], bb, acc[t_l][mt][yl], 0, 0, 0);
            acc[t_l][mt][yl] = __builtin_amdgcn_mfma_f32_16x16x32_bf16(a_cur[mt][1], bb, acc[t_l][mt][yl], 0, 0, 0);
            acc[t_l][mt][yl] = __builtin_amdgcn_mfma_f32_16x16x32_bf16(a_cur[mt][2], bb, acc[t_l][mt][yl], 0, 0, 0);
          }
        }
      }
#pragma unroll
      for (int mt = 0; mt < 2; ++mt)
#pragma unroll
        for (int sv = 0; sv < 3; ++sv) a_cur[mt][sv] = a_nxt[mt][sv];
    }

    // epilogue (LIF order: t_l 0 then 1)
#pragma unroll
    for (int t_l = 0; t_l < 2; ++t_l) {
#pragma unroll
      for (int mt = 0; mt < 2; ++mt)
#pragma unroll
        for (int reg = 0; reg < 4; ++reg) {
          float sarr[2];
#pragma unroll
          for (int yl = 0; yl < 2; ++yl) {
            float xv = fmaf(acc[t_l][mt][yl][reg], scr[mt][reg], shr[mt][reg]);
            float spk;
            LIF_STEP(v[mt][yl][reg], xv, spk);
            sarr[yl] = spk;
          }
          float hp0 = sarr[0] + __shfl_xor(sarr[0], 1);
          float hp1 = sarr[1] + __shfl_xor(sarr[1], 1);
          float vp = hp0 + hp1;
          if ((xl & 1) == 0) {
            int co = m0 + mt * 16 + q * 4 + reg;
            shout[t_l * 1088 + (xl >> 1) * 136 + co] = f2bf(0.25f * vp);
          }
        }
    }
    __syncthreads();
    // copy-out: pool2 [tb][s = q8*8 + px][ci]
    {
      int px = tid >> 5, ci4 = (tid & 31) * 4;
#pragma unroll
      for (int t_l = 0; t_l < 2; ++t_l) {
        uint2 vv = *(const uint2*)&shout[t_l * 1088 + px * 136 + ci4];
        *(uint2*)(pool2 + ((size_t)((tg * 2 + t_l) * 128 + b) * 64 + q8 * 8 + px) * 128 + ci4) = vv;
      }
    }
  }
}

// ---- fc1 (MFMA): partial[kb][o 256][tb 1024], split-K=16, no atomics; sB stride 42. ----
__global__ __launch_bounds__(256, 2) void fc1_mfma(const unsigned short* __restrict__ pool2,
    const unsigned short* __restrict__ B1, float* __restrict__ partial) {
  int bx = blockIdx.x;            // 512 = kb(16) x tbt(16) x t_o(2)
  int t_o = bx & 1, tbt = (bx >> 1) & 15, kb = bx >> 5;
  int tid = threadIdx.x, wave = tid >> 6, lane = tid & 63;
  int xl = lane & 15, q = lane >> 4;
  int m0 = t_o * 128 + wave * 32;
  int n0 = tbt * 64;
  __shared__ unsigned short sB[64 * 42];   // stride 42 shorts = 21 dwords (odd -> conflict-free)
  f32x4 acc[2][4];
#pragma unroll
  for (int mt = 0; mt < 2; ++mt)
#pragma unroll
    for (int nt = 0; nt < 4; ++nt) acc[mt][nt] = (f32x4){0.f, 0.f, 0.f, 0.f};

#pragma unroll 1
  for (int kc0 = 0; kc0 < 16; ++kc0) {
    int kc = kb * 16 + kc0;
    __syncthreads();
    {
      int tb_l = tid >> 2, kq = tid & 3;
      uint4 vv = *(const uint4*)(pool2 + (size_t)(n0 + tb_l) * 8192 + kc * 32 + kq * 8);
      *(uint4*)(sB + tb_l * 42 + kq * 8) = vv;
    }
    __syncthreads();
    short8 a[2][3];
#pragma unroll
    for (int mt = 0; mt < 2; ++mt) {
      int aoff = ((kc * 256 + m0 + mt * 16 + xl) * 4 + q) * 8;
      a[mt][0] = *(const short8*)(B1 + aoff);
      a[mt][1] = *(const short8*)(B1 + 2097152 + aoff);
      a[mt][2] = *(const short8*)(B1 + 4194304 + aoff);
    }
#pragma unroll
    for (int nt = 0; nt < 4; ++nt) {
      short8 bb = *(const short8*)(sB + (nt * 16 + xl) * 42 + q * 8);
#pragma unroll
      for (int mt = 0; mt < 2; ++mt) {
        acc[mt][nt] = __builtin_amdgcn_mfma_f32_16x16x32_bf16(a[mt][0], bb, acc[mt][nt], 0, 0, 0);
        acc[mt][nt] = __builtin_amdgcn_mfma_f32_16x16x32_bf16(a[mt][1], bb, acc[mt][nt], 0, 0, 0);
        acc[mt][nt] = __builtin_amdgcn_mfma_f32_16x16x32_bf16(a[mt][2], bb, acc[mt][nt], 0, 0, 0);
      }
    }
  }
#pragma unroll
  for (int mt = 0; mt < 2; ++mt)
#pragma unroll
    for (int nt = 0; nt < 4; ++nt)
#pragma unroll
      for (int reg = 0; reg < 4; ++reg) {
        int o = m0 + mt * 16 + q * 4 + reg;
        partial[((size_t)kb * 256 + o) * 1024 + n0 + nt * 16 + xl] = acc[mt][nt][reg];
      }
}

// ---- reduce partials + LIF -> fc1 spikes [t][b][o]. ----
__global__ __launch_bounds__(256) void reduce_lif(const float* __restrict__ partial, float* __restrict__ fs) {
  int idx = blockIdx.x * 256 + threadIdx.x;
  int o = idx >> 7, b = idx & 127;
  float v = 0.f;
#pragma unroll 1
  for (int t = 0; t < 8; ++t) {
    float xv = 0.f;
#pragma unroll
    for (int kb = 0; kb < 16; ++kb)
      xv += partial[((size_t)kb * 256 + o) * 1024 + t * 128 + b];
    float s;
    LIF_STEP(v, xv, s);
    fs[t * 32768 + b * 256 + o] = s;
  }
}

__global__ __launch_bounds__(256) void fc2_kernel(const float* __restrict__ fs, const float* __restrict__ w,
                                                  const float* __restrict__ bias, float* __restrict__ outp) {
  int tb = blockIdx.x;
  __shared__ float sv[256];
  int tid = threadIdx.x;
  sv[tid] = fs[tb * 256 + tid];
  __syncthreads();
  if (tid < 10) {
    float a = bias[tid];
    const float* wr = w + tid * 256;
#pragma unroll 8
    for (int o = 0; o < 256; ++o) a = fmaf(sv[o], wr[o], a);
    outp[tb * 10 + tid] = a;
  }
}

extern "C" void kernel_launch(void* const* d_in, const int* in_sizes, int n_in,
                              void* d_out, int out_size, void* d_ws, size_t ws_size,
                              hipStream_t stream) {
  (void)in_sizes; (void)n_in; (void)out_size; (void)ws_size;
  const float* x_seq   = (const float*)d_in[0];
  const float* conv1_w = (const float*)d_in[1];
  const float* bn1_g   = (const float*)d_in[2];
  const float* bn1_b   = (const float*)d_in[3];
  const float* conv2_w = (const float*)d_in[4];
  const float* bn2_g   = (const float*)d_in[5];
  const float* bn2_b   = (const float*)d_in[6];
  const float* fc1_w   = (const float*)d_in[7];
  const float* fc2_w   = (const float*)d_in[8];
  const float* fc2_b   = (const float*)d_in[9];
  float* out = (float*)d_out;
  float* ws  = (float*)d_ws;

  unsigned short* pool1 = (unsigned short*)(ws + OFF_POOL1);
  float* fc1_part = ws + OFF_POOL1;
  unsigned short* pool2 = (unsigned short*)(ws + OFF_POOL2);
  float* fc1_s   = ws + OFF_FC1S;
  unsigned short* A2 = (unsigned short*)(ws + OFF_A2);
  unsigned short* B1 = (unsigned short*)(ws + OFF_B1);
  float* st      = ws + OFF_STATS;
  float* s1_sum = st;        float* s1_sq  = st + 64;
  float* bn1_sc = st + 128;  float* bn1_sh = st + 192;
  float* bn2_sc = st + 256;  float* bn2_sh = st + 384;
  float* s2p    = st + 512;  // [64 sp][2][128]

  zero_kernel<<<66, 256, 0, stream>>>(st, STATS_N);
  prep_w2<<<288, 256, 0, stream>>>(conv2_w, A2);
  prep_b1<<<8192, 256, 0, stream>>>(fc1_w, B1);
  conv1_pass1<<<1024, 256, 0, stream>>>(x_seq, conv1_w, s1_sum, s1_sq);
  finalize_bn<<<1, 64, 0, stream>>>(s1_sum, s1_sq, bn1_g, bn1_b, bn1_sc, bn1_sh, 1.0f / 1048576.0f);
  conv1_fused<<<1024, 256, 0, stream>>>(x_seq, conv1_w, bn1_sc, bn1_sh, pool1);
  conv2_pass1_mfma<<<4096, 256, 0, stream>>>(pool1, A2, s2p);
  finalize_bn2<<<1, 128, 0, stream>>>(s2p, bn2_g, bn2_b, bn2_sc, bn2_sh, 1.0f / 262144.0f);
  conv2_fused_mfma<<<1024, 256, 0, stream>>>(pool1, A2, bn2_sc, bn2_sh, pool2);
  fc1_mfma<<<512, 256, 0, stream>>>(pool2, B1, fc1_part);
  reduce_lif<<<128, 256, 0, stream>>>(fc1_part, fc1_s);
  fc2_kernel<<<1024, 256, 0, stream>>>(fc1_s, fc2_w, fc2_b, out);
}

// Round 8
// 526.859 us; speedup vs baseline: 1.2240x; 1.2240x over previous
//
#include <hip/hip_runtime.h>

// SNN forward. conv2 + fc1 on MFMA bf16, 3-way weight splits (hi+lo+lolo).
// R8: conv2 computed ONCE (store kernel fuses BN stats + writes fp32 preact);
//     BN+LIF+pool is now a memory-bound pass over the stored preact.
//     conv2 LDS reverted to R6 un-padded layout (R7 padding doubled conflicts).
//     prep_b1 rewritten with LDS transpose (coalesced reads+writes).

#define LIF_STEP(vv, xx, ss) do { \
    vv = fmaf((xx) - vv, 0.5f, vv); \
    ss = (vv >= 1.0f) ? 1.0f : 0.0f; \
    vv = (vv >= 1.0f) ? 0.0f : vv; \
  } while (0)

typedef __attribute__((ext_vector_type(8))) short short8;
typedef __attribute__((ext_vector_type(4))) float f32x4;

__device__ __forceinline__ float bf2f(unsigned short u) {
  return __uint_as_float(((unsigned)u) << 16);
}
__device__ __forceinline__ unsigned short f2bf(float f) {
  return (unsigned short)(__float_as_uint(f) >> 16);  // exact for k/4 spike values
}

// ---- workspace layout (float-slot offsets) ----
// pool1 bf16 [1024 tb][8 cg][16 py][16 px][8 ci_l] = 16,777,216 u16 (8,388,608 f)
//   (reused AFTER conv2_store as fc1 partials f32 [16 kb][256 o][1024 tb])
// pool2 bf16 [1024 tb][64 s][128 ci] = 8,388,608 u16 (4,194,304 f)
// preact f32 [1024 tb][16 row][128 co][16 col] = 33,554,432 f
#define OFF_POOL1   0u
#define OFF_POOL2   8388608u
#define OFF_PRE     12582912u
#define OFF_STATS   46137344u   // f32 16,896
#define OFF_FC1S    46154240u   // f32 262,144
#define OFF_A2      46416384u   // bf16 3x[18 kc][128 co][4 q][8 j]
#define OFF_B1      46526976u   // bf16 3x[256 kc][256 o][4 q][8 j]
// total 49,672,704 floats = 198.7 MB
// stats sublayout: s1_sum(64) s1_sq(64) bn1_sc(64) bn1_sh(64)
//                  bn2_sc(128) bn2_sh(128) s2_part[64 sp][2][128]
#define STATS_N 16896u

__global__ __launch_bounds__(256) void zero_kernel(float* __restrict__ p, unsigned n) {
  unsigned i = blockIdx.x * 256u + threadIdx.x;
  if (i < n) p[i] = 0.0f;
}

// conv2_w [co 128][ci 64][dy 3][dx 3] fp32 -> 3-way bf16 split in MFMA A-frag order
__global__ __launch_bounds__(256) void prep_w2(const float* __restrict__ w, unsigned short* __restrict__ A2) {
  int i = blockIdx.x * 256 + threadIdx.x;
  if (i >= 73728) return;
  int co = i / 576, r = i - co * 576;
  int ci = r / 9, t9 = r - ci * 9;
  int k = t9 * 64 + ci;
  int kc = k >> 5, q = (k >> 3) & 3, j = k & 7;
  int off = ((kc * 128 + co) * 4 + q) * 8 + j;
  float wv = w[i];
  unsigned short hi = f2bf(wv);
  float rem = wv - bf2f(hi);
  unsigned short lo = f2bf(rem);
  float rem2 = rem - bf2f(lo);
  A2[off] = hi;
  A2[73728 + off] = lo;
  A2[147456 + off] = f2bf(rem2);
}

// fc1_w -> 3-way split via LDS transpose. Block = o-pair; reads AND writes coalesced.
// B1 slot for (o,k): kc*8192 + o*32 + (k&31), k = s*128+ci (pool2 is [s][ci], k_orig = ci*64+s).
__global__ __launch_bounds__(256) void prep_b1(const float* __restrict__ w, unsigned short* __restrict__ B1) {
  __shared__ unsigned short sh[2][8192];
  int blk = blockIdx.x;        // 128 o-pairs
  int tid = threadIdx.x;
  for (int sv = 0; sv < 3; ++sv) {
    __syncthreads();
    for (int o_l = 0; o_l < 2; ++o_l) {
      for (int it = 0; it < 32; ++it) {
        int korig = tid + 256 * it;
        float wv = w[(size_t)(blk * 2 + o_l) * 8192 + korig];
        unsigned short hi = f2bf(wv);
        float rem = wv - bf2f(hi);
        unsigned short lo = f2bf(rem);
        unsigned short pc = (sv == 0) ? hi : (sv == 1) ? lo : f2bf(rem - bf2f(lo));
        int k = (korig & 63) * 128 + (korig >> 6);
        sh[o_l][k] = pc;
      }
    }
    __syncthreads();
    unsigned short* outp = B1 + (size_t)sv * 2097152;
    for (int it = 0; it < 64; ++it) {
      int idx = tid + 256 * it;        // 16384
      int kc = idx >> 6, r = idx & 63;
      int o_l = r >> 5, m = r & 31;
      outp[kc * 8192 + blk * 64 + r] = sh[o_l][kc * 32 + m];
    }
  }
}

// ---- conv1 pass 1: stats only. (validated) ----
__global__ __launch_bounds__(256) void conv1_pass1(const float* __restrict__ x,
                                                   const float* __restrict__ w,
                                                   float* __restrict__ s_sum,
                                                   float* __restrict__ s_sq) {
  int tb = blockIdx.x;
  __shared__ float simg[3 * 32 * 36];
  int tid = threadIdx.x;
  const float* xb = x + tb * 3072;
  for (int i = tid; i < 3456; i += 256) {
    int ci = i / 1152, rem = i - ci * 1152;
    int y = rem / 36, px = rem - y * 36;
    int gx = px - 1;
    simg[i] = ((unsigned)gx < 32u) ? xb[(ci * 32 + y) * 32 + gx] : 0.0f;
  }
  __syncthreads();

  int cgrp = tid >> 3, rowthr = tid & 7;
  int c0 = cgrp * 2;
  float w0[27], w1[27];
#pragma unroll
  for (int j = 0; j < 27; ++j) { w0[j] = w[c0 * 27 + j]; w1[j] = w[c0 * 27 + 27 + j]; }

  float s1a = 0.f, s2a = 0.f, s1b = 0.f, s2b = 0.f;
  for (int task = 0; task < 8; ++task) {
    int y = rowthr + (task & 3) * 8;
    int x0 = (task >> 2) * 16;
    float acc0[16] = {0.f,0.f,0.f,0.f,0.f,0.f,0.f,0.f,0.f,0.f,0.f,0.f,0.f,0.f,0.f,0.f};
    float acc1[16] = {0.f,0.f,0.f,0.f,0.f,0.f,0.f,0.f,0.f,0.f,0.f,0.f,0.f,0.f,0.f,0.f};
#pragma unroll
    for (int ci = 0; ci < 3; ++ci) {
#pragma unroll
      for (int dy = 0; dy < 3; ++dy) {
        int yy = y + dy - 1;
        if (yy >= 0 && yy < 32) {
          const float* row = simg + (ci * 32 + yy) * 36 + x0;
          float rr[20];
#pragma unroll
          for (int q = 0; q < 5; ++q) {
            float4 f = *(const float4*)(row + q * 4);
            rr[q*4+0] = f.x; rr[q*4+1] = f.y; rr[q*4+2] = f.z; rr[q*4+3] = f.w;
          }
#pragma unroll
          for (int dx = 0; dx < 3; ++dx) {
            float wa = w0[ci*9 + dy*3 + dx], wb = w1[ci*9 + dy*3 + dx];
#pragma unroll
            for (int xi = 0; xi < 16; ++xi) {
              float v = rr[xi + dx];
              acc0[xi] = fmaf(wa, v, acc0[xi]);
              acc1[xi] = fmaf(wb, v, acc1[xi]);
            }
          }
        }
      }
    }
#pragma unroll
    for (int xi = 0; xi < 16; ++xi) {
      s1a += acc0[xi]; s2a = fmaf(acc0[xi], acc0[xi], s2a);
      s1b += acc1[xi]; s2b = fmaf(acc1[xi], acc1[xi], s2b);
    }
  }
#pragma unroll
  for (int off = 1; off < 8; off <<= 1) {
    s1a += __shfl_xor(s1a, off); s2a += __shfl_xor(s2a, off);
    s1b += __shfl_xor(s1b, off); s2b += __shfl_xor(s2b, off);
  }
  if (rowthr == 0) {
    atomicAdd(&s_sum[c0], s1a);     atomicAdd(&s_sq[c0], s2a);
    atomicAdd(&s_sum[c0 + 1], s1b); atomicAdd(&s_sq[c0 + 1], s2b);
  }
}

__global__ void finalize_bn(const float* __restrict__ sum, const float* __restrict__ sq,
                            const float* __restrict__ g, const float* __restrict__ b,
                            float* __restrict__ scale, float* __restrict__ shift, float inv_n) {
  int c = threadIdx.x;
  float mean = sum[c] * inv_n;
  float var = fmaxf(sq[c] * inv_n - mean * mean, 0.0f);
  float rstd = rsqrtf(var + 1e-5f);
  float sc = g[c] * rstd;
  scale[c] = sc;
  shift[c] = fmaf(-mean, sc, b[c]);
}

// layer-2 finalize: reduce 64-way spread partials [sp][2][128]
__global__ void finalize_bn2(const float* __restrict__ s2p,
                             const float* __restrict__ g, const float* __restrict__ b,
                             float* __restrict__ scale, float* __restrict__ shift, float inv_n) {
  int c = threadIdx.x;   // 128
  float s1 = 0.f, s2 = 0.f;
#pragma unroll 8
  for (int sp = 0; sp < 64; ++sp) {
    s1 += s2p[sp * 256 + c];
    s2 += s2p[sp * 256 + 128 + c];
  }
  float mean = s1 * inv_n;
  float var = fmaxf(s2 * inv_n - mean * mean, 0.0f);
  float rstd = rsqrtf(var + 1e-5f);
  float sc = g[c] * rstd;
  scale[c] = sc;
  shift[c] = fmaf(-mean, sc, b[c]);
}

// ---- conv1 pass 2: fused conv+BN+LIF+pool -> pool1 [tb][cg][py][px][ci_l 8]. (validated) ----
__global__ __launch_bounds__(256) void conv1_fused(const float* __restrict__ x,
    const float* __restrict__ w, const float* __restrict__ scale, const float* __restrict__ shift,
    unsigned short* __restrict__ pool1) {
  int b = blockIdx.x >> 3, cg = blockIdx.x & 7;
  int tid = threadIdx.x;
  int co_l = tid >> 5;
  int co = cg * 8 + co_l;
  int y = tid & 31;
  __shared__ float simg[3 * 34 * 36];
  __shared__ unsigned short shp[2112];
  float wreg[27];
#pragma unroll
  for (int j = 0; j < 27; ++j) wreg[j] = w[co * 27 + j];
  float sc = scale[co], sh = shift[co];
  float v[32];
#pragma unroll
  for (int i = 0; i < 32; ++i) v[i] = 0.f;

  for (int t = 0; t < 8; ++t) {
    int tb = t * 128 + b;
    const float* xb = x + tb * 3072;
    __syncthreads();
    for (int i = tid; i < 3672; i += 256) {
      int ci = i / 1224, r = i - ci * 1224;
      int yy = r / 36, xx = r - yy * 36;
      int gy = yy - 1, gx = xx - 1;
      simg[i] = ((unsigned)gy < 32u && (unsigned)gx < 32u) ? xb[(ci * 32 + gy) * 32 + gx] : 0.f;
    }
    __syncthreads();
    float acc[32];
#pragma unroll
    for (int i = 0; i < 32; ++i) acc[i] = 0.f;
#pragma unroll
    for (int ci = 0; ci < 3; ++ci) {
#pragma unroll
      for (int dy = 0; dy < 3; ++dy) {
        const float* row = simg + (ci * 34 + y + dy) * 36;
        float rr[36];
#pragma unroll
        for (int q = 0; q < 9; ++q) {
          float4 f = *(const float4*)(row + q * 4);
          rr[q*4+0]=f.x; rr[q*4+1]=f.y; rr[q*4+2]=f.z; rr[q*4+3]=f.w;
        }
#pragma unroll
        for (int dx = 0; dx < 3; ++dx) {
          float wv = wreg[ci * 9 + dy * 3 + dx];
#pragma unroll
          for (int xx2 = 0; xx2 < 32; ++xx2)
            acc[xx2] = fmaf(wv, rr[xx2 + dx], acc[xx2]);
        }
      }
    }
    float hp[16];
#pragma unroll
    for (int px = 0; px < 16; ++px) {
      float s0, s1, xv;
      xv = fmaf(acc[2*px],   sc, sh); LIF_STEP(v[2*px],   xv, s0);
      xv = fmaf(acc[2*px+1], sc, sh); LIF_STEP(v[2*px+1], xv, s1);
      hp[px] = s0 + s1;
    }
    unsigned short ob[16];
#pragma unroll
    for (int px = 0; px < 16; ++px) {
      float sum = hp[px] + __shfl_xor(hp[px], 1);
      ob[px] = f2bf(0.25f * sum);
    }
    if ((y & 1) == 0) {
      int py = y >> 1;
#pragma unroll
      for (int px = 0; px < 16; ++px)
        shp[py * 132 + px * 8 + co_l] = ob[px];
    }
    __syncthreads();
    {
      int o = (tid >> 4) * 132 + (tid & 15) * 8;
      uint2 lo = *(const uint2*)&shp[o];
      uint2 hi = *(const uint2*)&shp[o + 4];
      *(uint4*)(pool1 + (size_t)tb * 16384 + cg * 2048 + tid * 8) = make_uint4(lo.x, lo.y, hi.x, hi.y);
    }
  }
}

// ---- conv2 (MFMA, single pass): stats + fp32 preact store. Block = (tb, row-quarter). ----
// R6 un-padded LDS layout [row 6][cg 8][x 18][ci_l 8]; A-frag prefetch.
__global__ __launch_bounds__(256, 2) void conv2_store_mfma(const unsigned short* __restrict__ pool1,
    const unsigned short* __restrict__ A2, float* __restrict__ preact, float* __restrict__ s2p) {
  int bx = blockIdx.x;
  int tb = bx >> 2, q4 = bx & 3;
  int sp = bx & 63;
  __shared__ unsigned short simg[6 * 8 * 18 * 8];   // 13,824 B
  int tid = threadIdx.x;
  const unsigned* src = (const unsigned*)(pool1 + (size_t)tb * 16384);
  unsigned* dstw = (unsigned*)simg;
  for (int i = tid; i < 3456; i += 256) {
    int cp = i & 3, rest = i >> 2;
    int jj = rest / 18, xx = rest - jj * 18;
    int cg = jj & 7, row_l = jj >> 3;
    int yi = q4 * 4 - 1 + row_l, gx = xx - 1;
    unsigned val = 0u;
    if ((unsigned)yi < 16u && (unsigned)gx < 16u)
      val = src[cg * 1024 + yi * 64 + gx * 4 + cp];
    dstw[i] = val;
  }
  __syncthreads();

  int wave = tid >> 6, lane = tid & 63;
  int xl = lane & 15, q = lane >> 4;
  int m0 = wave * 32;
  f32x4 acc[2][4];
#pragma unroll
  for (int mt = 0; mt < 2; ++mt)
#pragma unroll
    for (int yl = 0; yl < 4; ++yl) acc[mt][yl] = (f32x4){0.f, 0.f, 0.f, 0.f};

  short8 a_cur[2][3];
#pragma unroll
  for (int mt = 0; mt < 2; ++mt) {
    int aoff = ((m0 + mt * 16 + xl) * 4 + q) * 8;
    a_cur[mt][0] = *(const short8*)(A2 + aoff);
    a_cur[mt][1] = *(const short8*)(A2 + 73728 + aoff);
    a_cur[mt][2] = *(const short8*)(A2 + 147456 + aoff);
  }

#pragma unroll 1
  for (int kc = 0; kc < 18; ++kc) {
    short8 a_nxt[2][3];
    if (kc < 17) {
#pragma unroll
      for (int mt = 0; mt < 2; ++mt) {
        int aoff = (((kc + 1) * 128 + m0 + mt * 16 + xl) * 4 + q) * 8;
        a_nxt[mt][0] = *(const short8*)(A2 + aoff);
        a_nxt[mt][1] = *(const short8*)(A2 + 73728 + aoff);
        a_nxt[mt][2] = *(const short8*)(A2 + 147456 + aoff);
      }
    } else {
#pragma unroll
      for (int mt = 0; mt < 2; ++mt)
#pragma unroll
        for (int sv = 0; sv < 3; ++sv) a_nxt[mt][sv] = a_cur[mt][sv];
    }
    int tap = kc >> 1;
    int dy = tap / 3, dx = tap - dy * 3;
    int cgq = (kc & 1) * 4 + q;
#pragma unroll
    for (int yl = 0; yl < 4; ++yl) {
      int baddr = (((yl + dy) * 8 + cgq) * 18 + (xl + dx)) * 8;
      short8 bb = *(const short8*)(simg + baddr);
#pragma unroll
      for (int mt = 0; mt < 2; ++mt) {
        acc[mt][yl] = __builtin_amdgcn_mfma_f32_16x16x32_bf16(a_cur[mt][0], bb, acc[mt][yl], 0, 0, 0);
        acc[mt][yl] = __builtin_amdgcn_mfma_f32_16x16x32_bf16(a_cur[mt][1], bb, acc[mt][yl], 0, 0, 0);
        acc[mt][yl] = __builtin_amdgcn_mfma_f32_16x16x32_bf16(a_cur[mt][2], bb, acc[mt][yl], 0, 0, 0);
      }
    }
#pragma unroll
    for (int mt = 0; mt < 2; ++mt)
#pragma unroll
      for (int sv = 0; sv < 3; ++sv) a_cur[mt][sv] = a_nxt[mt][sv];
  }

  // epilogue: store preact [tb][row][co][col] + fused BN stats
  float* pre = preact + (size_t)tb * 32768;
#pragma unroll
  for (int mt = 0; mt < 2; ++mt)
#pragma unroll
    for (int reg = 0; reg < 4; ++reg) {
      int co = m0 + mt * 16 + q * 4 + reg;
      float s1 = 0.f, s2 = 0.f;
#pragma unroll
      for (int yl = 0; yl < 4; ++yl) {
        float val = acc[mt][yl][reg];
        int row = q4 * 4 + yl;
        pre[(row * 128 + co) * 16 + xl] = val;
        s1 += val; s2 = fmaf(val, val, s2);
      }
#pragma unroll
      for (int off = 1; off < 16; off <<= 1) {
        s1 += __shfl_xor(s1, off); s2 += __shfl_xor(s2, off);
      }
      if (xl == 0) {
        atomicAdd(&s2p[sp * 256 + co], s1);
        atomicAdd(&s2p[sp * 256 + 128 + co], s2);
      }
    }
}

// ---- BN2 + LIF + pool over stored preact. Block = (b, row-quarter); grid 512. ----
// thread = (co, col-half); 8 pooled outputs, 32 membranes; coalesced reads; LDS-transposed writes.
__global__ __launch_bounds__(256) void bn2_lif_pool(const float* __restrict__ pre,
    const float* __restrict__ scale, const float* __restrict__ shift,
    unsigned short* __restrict__ pool2) {
  int b = blockIdx.x >> 2, q4 = blockIdx.x & 3;
  int tid = threadIdx.x;
  int co = tid >> 1, half = tid & 1;
  __shared__ unsigned short shout[16 * 136];
  float sc = scale[co], sh = shift[co];
  float v[2][4][4];   // [py_l][p][window elem r*2+c]
#pragma unroll
  for (int a = 0; a < 2; ++a)
#pragma unroll
    for (int p = 0; p < 4; ++p)
#pragma unroll
      for (int e = 0; e < 4; ++e) v[a][p][e] = 0.f;

#pragma unroll 1
  for (int t = 0; t < 8; ++t) {
    const float* base = pre + ((size_t)((t * 128 + b) * 16 + q4 * 4)) * 2048 + co * 16 + half * 8;
    __syncthreads();   // shout free from previous copy-out
#pragma unroll
    for (int py_l = 0; py_l < 2; ++py_l) {
      float4 r0a = *(const float4*)(base + (py_l * 2) * 2048);
      float4 r0b = *(const float4*)(base + (py_l * 2) * 2048 + 4);
      float4 r1a = *(const float4*)(base + (py_l * 2 + 1) * 2048);
      float4 r1b = *(const float4*)(base + (py_l * 2 + 1) * 2048 + 4);
      float p00[4] = {r0a.x, r0a.z, r0b.x, r0b.z};
      float p01[4] = {r0a.y, r0a.w, r0b.y, r0b.w};
      float p10[4] = {r1a.x, r1a.z, r1b.x, r1b.z};
      float p11[4] = {r1a.y, r1a.w, r1b.y, r1b.w};
#pragma unroll
      for (int p = 0; p < 4; ++p) {
        float s00, s01, s10, s11, xv;
        xv = fmaf(p00[p], sc, sh); LIF_STEP(v[py_l][p][0], xv, s00);
        xv = fmaf(p01[p], sc, sh); LIF_STEP(v[py_l][p][1], xv, s01);
        xv = fmaf(p10[p], sc, sh); LIF_STEP(v[py_l][p][2], xv, s10);
        xv = fmaf(p11[p], sc, sh); LIF_STEP(v[py_l][p][3], xv, s11);
        int s_l = py_l * 8 + half * 4 + p;
        shout[s_l * 136 + co] = f2bf(0.25f * (s00 + s01 + s10 + s11));
      }
    }
    __syncthreads();
    {
      int s_l = tid >> 4, ci8 = (tid & 15) * 8;
      uint4 vv = *(const uint4*)&shout[s_l * 136 + ci8];
      *(uint4*)(pool2 + ((size_t)(t * 128 + b) * 64 + q4 * 16 + s_l) * 128 + ci8) = vv;
    }
  }
}

// ---- fc1 (MFMA): partial[kb][o 256][tb 1024], split-K=16, no atomics. (validated) ----
__global__ __launch_bounds__(256, 2) void fc1_mfma(const unsigned short* __restrict__ pool2,
    const unsigned short* __restrict__ B1, float* __restrict__ partial) {
  int bx = blockIdx.x;            // 512 = kb(16) x tbt(16) x t_o(2)
  int t_o = bx & 1, tbt = (bx >> 1) & 15, kb = bx >> 5;
  int tid = threadIdx.x, wave = tid >> 6, lane = tid & 63;
  int xl = lane & 15, q = lane >> 4;
  int m0 = t_o * 128 + wave * 32;
  int n0 = tbt * 64;
  __shared__ unsigned short sB[64 * 42];
  f32x4 acc[2][4];
#pragma unroll
  for (int mt = 0; mt < 2; ++mt)
#pragma unroll
    for (int nt = 0; nt < 4; ++nt) acc[mt][nt] = (f32x4){0.f, 0.f, 0.f, 0.f};

#pragma unroll 1
  for (int kc0 = 0; kc0 < 16; ++kc0) {
    int kc = kb * 16 + kc0;
    __syncthreads();
    {
      int tb_l = tid >> 2, kq = tid & 3;
      uint4 vv = *(const uint4*)(pool2 + (size_t)(n0 + tb_l) * 8192 + kc * 32 + kq * 8);
      *(uint4*)(sB + tb_l * 42 + kq * 8) = vv;
    }
    __syncthreads();
    short8 a[2][3];
#pragma unroll
    for (int mt = 0; mt < 2; ++mt) {
      int aoff = ((kc * 256 + m0 + mt * 16 + xl) * 4 + q) * 8;
      a[mt][0] = *(const short8*)(B1 + aoff);
      a[mt][1] = *(const short8*)(B1 + 2097152 + aoff);
      a[mt][2] = *(const short8*)(B1 + 4194304 + aoff);
    }
#pragma unroll
    for (int nt = 0; nt < 4; ++nt) {
      short8 bb = *(const short8*)(sB + (nt * 16 + xl) * 42 + q * 8);
#pragma unroll
      for (int mt = 0; mt < 2; ++mt) {
        acc[mt][nt] = __builtin_amdgcn_mfma_f32_16x16x32_bf16(a[mt][0], bb, acc[mt][nt], 0, 0, 0);
        acc[mt][nt] = __builtin_amdgcn_mfma_f32_16x16x32_bf16(a[mt][1], bb, acc[mt][nt], 0, 0, 0);
        acc[mt][nt] = __builtin_amdgcn_mfma_f32_16x16x32_bf16(a[mt][2], bb, acc[mt][nt], 0, 0, 0);
      }
    }
  }
#pragma unroll
  for (int mt = 0; mt < 2; ++mt)
#pragma unroll
    for (int nt = 0; nt < 4; ++nt)
#pragma unroll
      for (int reg = 0; reg < 4; ++reg) {
        int o = m0 + mt * 16 + q * 4 + reg;
        partial[((size_t)kb * 256 + o) * 1024 + n0 + nt * 16 + xl] = acc[mt][nt][reg];
      }
}

// ---- reduce partials + LIF -> fc1 spikes [t][b][o]. ----
__global__ __launch_bounds__(256) void reduce_lif(const float* __restrict__ partial, float* __restrict__ fs) {
  int idx = blockIdx.x * 256 + threadIdx.x;
  int o = idx >> 7, b = idx & 127;
  float v = 0.f;
#pragma unroll 1
  for (int t = 0; t < 8; ++t) {
    float xv = 0.f;
#pragma unroll
    for (int kb = 0; kb < 16; ++kb)
      xv += partial[((size_t)kb * 256 + o) * 1024 + t * 128 + b];
    float s;
    LIF_STEP(v, xv, s);
    fs[t * 32768 + b * 256 + o] = s;
  }
}

__global__ __launch_bounds__(256) void fc2_kernel(const float* __restrict__ fs, const float* __restrict__ w,
                                                  const float* __restrict__ bias, float* __restrict__ outp) {
  int tb = blockIdx.x;
  __shared__ float sv[256];
  int tid = threadIdx.x;
  sv[tid] = fs[tb * 256 + tid];
  __syncthreads();
  if (tid < 10) {
    float a = bias[tid];
    const float* wr = w + tid * 256;
#pragma unroll 8
    for (int o = 0; o < 256; ++o) a = fmaf(sv[o], wr[o], a);
    outp[tb * 10 + tid] = a;
  }
}

extern "C" void kernel_launch(void* const* d_in, const int* in_sizes, int n_in,
                              void* d_out, int out_size, void* d_ws, size_t ws_size,
                              hipStream_t stream) {
  (void)in_sizes; (void)n_in; (void)out_size; (void)ws_size;
  const float* x_seq   = (const float*)d_in[0];
  const float* conv1_w = (const float*)d_in[1];
  const float* bn1_g   = (const float*)d_in[2];
  const float* bn1_b   = (const float*)d_in[3];
  const float* conv2_w = (const float*)d_in[4];
  const float* bn2_g   = (const float*)d_in[5];
  const float* bn2_b   = (const float*)d_in[6];
  const float* fc1_w   = (const float*)d_in[7];
  const float* fc2_w   = (const float*)d_in[8];
  const float* fc2_b   = (const float*)d_in[9];
  float* out = (float*)d_out;
  float* ws  = (float*)d_ws;

  unsigned short* pool1 = (unsigned short*)(ws + OFF_POOL1);
  float* fc1_part = ws + OFF_POOL1;              // pool1 dead after conv2_store
  unsigned short* pool2 = (unsigned short*)(ws + OFF_POOL2);
  float* preact  = ws + OFF_PRE;
  float* fc1_s   = ws + OFF_FC1S;
  unsigned short* A2 = (unsigned short*)(ws + OFF_A2);
  unsigned short* B1 = (unsigned short*)(ws + OFF_B1);
  float* st      = ws + OFF_STATS;
  float* s1_sum = st;        float* s1_sq  = st + 64;
  float* bn1_sc = st + 128;  float* bn1_sh = st + 192;
  float* bn2_sc = st + 256;  float* bn2_sh = st + 384;
  float* s2p    = st + 512;  // [64 sp][2][128]

  zero_kernel<<<66, 256, 0, stream>>>(st, STATS_N);
  prep_w2<<<288, 256, 0, stream>>>(conv2_w, A2);
  prep_b1<<<128, 256, 0, stream>>>(fc1_w, B1);
  conv1_pass1<<<1024, 256, 0, stream>>>(x_seq, conv1_w, s1_sum, s1_sq);
  finalize_bn<<<1, 64, 0, stream>>>(s1_sum, s1_sq, bn1_g, bn1_b, bn1_sc, bn1_sh, 1.0f / 1048576.0f);
  conv1_fused<<<1024, 256, 0, stream>>>(x_seq, conv1_w, bn1_sc, bn1_sh, pool1);
  conv2_store_mfma<<<4096, 256, 0, stream>>>(pool1, A2, preact, s2p);
  finalize_bn2<<<1, 128, 0, stream>>>(s2p, bn2_g, bn2_b, bn2_sc, bn2_sh, 1.0f / 262144.0f);
  bn2_lif_pool<<<512, 256, 0, stream>>>(preact, bn2_sc, bn2_sh, pool2);
  fc1_mfma<<<512, 256, 0, stream>>>(pool2, B1, fc1_part);
  reduce_lif<<<128, 256, 0, stream>>>(fc1_part, fc1_s);
  fc2_kernel<<<1024, 256, 0, stream>>>(fc1_s, fc2_w, fc2_b, out);
}

// Round 9
// 416.838 us; speedup vs baseline: 1.5470x; 1.2639x over previous
//
#include <hip/hip_runtime.h>

// SNN forward — all three heavy ops (conv1, conv2, fc1) on MFMA bf16.
// conv1 (R9): register-built im2col, K=27->32; x 3-way bf16 split (fp32 input),
//   w 3-way split, 8 MFMA products (error ~2^-20 rel, same class as conv2 path).
// conv2: single pass, stats fused, fp32 preact stored; BN+LIF+pool memory pass.
// fc1: split-K=16 private partials, no atomics.

#define LIF_STEP(vv, xx, ss) do { \
    vv = fmaf((xx) - vv, 0.5f, vv); \
    ss = (vv >= 1.0f) ? 1.0f : 0.0f; \
    vv = (vv >= 1.0f) ? 0.0f : vv; \
  } while (0)

typedef __attribute__((ext_vector_type(8))) short short8;
typedef __attribute__((ext_vector_type(4))) float f32x4;

__device__ __forceinline__ float bf2f(unsigned short u) {
  return __uint_as_float(((unsigned)u) << 16);
}
__device__ __forceinline__ unsigned short f2bf(float f) {
  return (unsigned short)(__float_as_uint(f) >> 16);  // truncation split
}

// ---- workspace layout (float-slot offsets) ----
// pool1 bf16 [1024 tb][8 cg][16 py][16 px][8 ci_l] = 16,777,216 u16 (8,388,608 f)
//   (reused AFTER conv2_store as fc1 partials f32 [16 kb][256 o][1024 tb])
// pool2 bf16 [1024 tb][64 s][128 ci] = 8,388,608 u16 (4,194,304 f)
// preact f32 [1024 tb][16 row][128 co][16 col] = 33,554,432 f
#define OFF_POOL1   0u
#define OFF_POOL2   8388608u
#define OFF_PRE     12582912u
#define OFF_STATS   46137344u   // f32 24,960 (see sublayout)
#define OFF_FC1S    46162304u   // f32 262,144
#define OFF_A2      46424448u   // bf16 3x[18 kc][128 co][4 q][8 j] (110,592 f)
#define OFF_B1      46535040u   // bf16 3x[256 kc][256 o][4 q][8 j] (3,145,728 f)
#define OFF_A1      49680768u   // bf16 3x[64 co][32 k] (3,072 f)
// total 49,683,840 floats = 198.7 MB
// stats sublayout: s1p[64 sp][2][64] (8192) | s2p[64 sp][2][128] (16384)
//                  bn1_sc(64) bn1_sh(64) bn2_sc(128) bn2_sh(128)
#define ZERO_STATS 24576u

__global__ __launch_bounds__(256) void zero_kernel(float* __restrict__ p, unsigned n) {
  unsigned i = blockIdx.x * 256u + threadIdx.x;
  if (i < n) p[i] = 0.0f;
}

// conv1_w [64 co][3 ci][3 ky][3 kx] -> A1[sv][co][k], k = tap*3+ci (tap=ky*3+kx), k>=27 zero
__global__ __launch_bounds__(256) void prep_w1(const float* __restrict__ w, unsigned short* __restrict__ A1) {
  int i = blockIdx.x * 256 + threadIdx.x;
  if (i >= 2048) return;
  int co = i >> 5, k = i & 31;
  float wv = 0.f;
  if (k < 27) {
    int tap = k / 3, ci = k - tap * 3;
    wv = w[co * 27 + ci * 9 + tap];
  }
  unsigned short hi = f2bf(wv);
  float rem = wv - bf2f(hi);
  unsigned short lo = f2bf(rem);
  float rem2 = rem - bf2f(lo);
  A1[i] = hi;
  A1[2048 + i] = lo;
  A1[4096 + i] = f2bf(rem2);
}

// conv2_w [co 128][ci 64][3][3] -> 3-way bf16 split in MFMA A-frag order (validated)
__global__ __launch_bounds__(256) void prep_w2(const float* __restrict__ w, unsigned short* __restrict__ A2) {
  int i = blockIdx.x * 256 + threadIdx.x;
  if (i >= 73728) return;
  int co = i / 576, r = i - co * 576;
  int ci = r / 9, t9 = r - ci * 9;
  int k = t9 * 64 + ci;
  int kc = k >> 5, q = (k >> 3) & 3, j = k & 7;
  int off = ((kc * 128 + co) * 4 + q) * 8 + j;
  float wv = w[i];
  unsigned short hi = f2bf(wv);
  float rem = wv - bf2f(hi);
  unsigned short lo = f2bf(rem);
  float rem2 = rem - bf2f(lo);
  A2[off] = hi;
  A2[73728 + off] = lo;
  A2[147456 + off] = f2bf(rem2);
}

// fc1_w -> 3-way split via LDS transpose (validated R8)
__global__ __launch_bounds__(256) void prep_b1(const float* __restrict__ w, unsigned short* __restrict__ B1) {
  __shared__ unsigned short sh[2][8192];
  int blk = blockIdx.x;        // 128 o-pairs
  int tid = threadIdx.x;
  for (int sv = 0; sv < 3; ++sv) {
    __syncthreads();
    for (int o_l = 0; o_l < 2; ++o_l) {
      for (int it = 0; it < 32; ++it) {
        int korig = tid + 256 * it;
        float wv = w[(size_t)(blk * 2 + o_l) * 8192 + korig];
        unsigned short hi = f2bf(wv);
        float rem = wv - bf2f(hi);
        unsigned short lo = f2bf(rem);
        unsigned short pc = (sv == 0) ? hi : (sv == 1) ? lo : f2bf(rem - bf2f(lo));
        int k = (korig & 63) * 128 + (korig >> 6);
        sh[o_l][k] = pc;
      }
    }
    __syncthreads();
    unsigned short* outp = B1 + (size_t)sv * 2097152;
    for (int it = 0; it < 64; ++it) {
      int idx = tid + 256 * it;
      int kc = idx >> 6, r = idx & 63;
      int o_l = r >> 5, m = r & 31;
      outp[kc * 8192 + blk * 64 + r] = sh[o_l][kc * 32 + m];
    }
  }
}

// layer-1 finalize: reduce 64-way spread partials [sp][2][64]
__global__ void finalize_bn1(const float* __restrict__ s1p,
                             const float* __restrict__ g, const float* __restrict__ b,
                             float* __restrict__ scale, float* __restrict__ shift, float inv_n) {
  int c = threadIdx.x;   // 64
  float s1 = 0.f, s2 = 0.f;
#pragma unroll 8
  for (int sp = 0; sp < 64; ++sp) {
    s1 += s1p[sp * 128 + c];
    s2 += s1p[sp * 128 + 64 + c];
  }
  float mean = s1 * inv_n;
  float var = fmaxf(s2 * inv_n - mean * mean, 0.0f);
  float rstd = rsqrtf(var + 1e-5f);
  float sc = g[c] * rstd;
  scale[c] = sc;
  shift[c] = fmaf(-mean, sc, b[c]);
}

// layer-2 finalize: reduce 64-way spread partials [sp][2][128]
__global__ void finalize_bn2(const float* __restrict__ s2p,
                             const float* __restrict__ g, const float* __restrict__ b,
                             float* __restrict__ scale, float* __restrict__ shift, float inv_n) {
  int c = threadIdx.x;   // 128
  float s1 = 0.f, s2 = 0.f;
#pragma unroll 8
  for (int sp = 0; sp < 64; ++sp) {
    s1 += s2p[sp * 256 + c];
    s2 += s2p[sp * 256 + 128 + c];
  }
  float mean = s1 * inv_n;
  float var = fmaxf(s2 * inv_n - mean * mean, 0.0f);
  float rstd = rsqrtf(var + 1e-5f);
  float sc = g[c] * rstd;
  scale[c] = sc;
  shift[c] = fmaf(-mean, sc, b[c]);
}

// ---- conv1 pass 1 (MFMA im2col): stats only. Block = (b, yq 8) -> 4 rows; wave = row. ----
__global__ __launch_bounds__(256) void conv1_pass1_mfma(const float* __restrict__ x,
    const unsigned short* __restrict__ A1, float* __restrict__ s1p) {
  int b = blockIdx.x >> 3, yq = blockIdx.x & 7;
  int y0 = yq * 4;
  int sp = blockIdx.x & 63;
  int tid = threadIdx.x, wave = tid >> 6, lane = tid & 63;
  int xl = lane & 15, q = lane >> 4;
  __shared__ float xs[648];   // [ci 3][row 6][col 36] padded
  short8 A[3][4];
#pragma unroll
  for (int mt = 0; mt < 4; ++mt) {
    int aoff = (mt * 16 + xl) * 32 + q * 8;
    A[0][mt] = *(const short8*)(A1 + aoff);
    A[1][mt] = *(const short8*)(A1 + 2048 + aoff);
    A[2][mt] = *(const short8*)(A1 + 4096 + aoff);
  }
  int cb[8]; bool vld[8];
#pragma unroll
  for (int j = 0; j < 8; ++j) {
    int k = q * 8 + j;
    int tap = k / 3, ci = k - tap * 3;
    int dy = tap / 3, dx = tap - dy * 3;
    vld[j] = (k < 27);
    cb[j] = ci * 216 + (wave + dy) * 36 + dx + xl;
  }
  float s1[4][4], s2[4][4];
#pragma unroll
  for (int mt = 0; mt < 4; ++mt)
#pragma unroll
    for (int reg = 0; reg < 4; ++reg) { s1[mt][reg] = 0.f; s2[mt][reg] = 0.f; }

#pragma unroll 1
  for (int t = 0; t < 8; ++t) {
    int tb = t * 128 + b;
    const float* xb = x + tb * 3072;
    __syncthreads();
    for (int i = tid; i < 648; i += 256) {
      int ci = i / 216, r1 = i - ci * 216;
      int rr = r1 / 36, c = r1 - rr * 36;
      int gy = y0 - 1 + rr, gx = c - 1;
      xs[i] = ((unsigned)gy < 32u && (unsigned)gx < 32u) ? xb[(ci * 32 + gy) * 32 + gx] : 0.f;
    }
    __syncthreads();
    f32x4 acc[2][4];
#pragma unroll
    for (int tile = 0; tile < 2; ++tile)
#pragma unroll
      for (int mt = 0; mt < 4; ++mt) acc[tile][mt] = (f32x4){0.f, 0.f, 0.f, 0.f};
#pragma unroll
    for (int tile = 0; tile < 2; ++tile) {
      short8 Bh = (short8){0,0,0,0,0,0,0,0};
      short8 Bl = (short8){0,0,0,0,0,0,0,0};
      short8 Bll = (short8){0,0,0,0,0,0,0,0};
#pragma unroll
      for (int j = 0; j < 8; ++j) {
        float xv = vld[j] ? xs[cb[j] + tile * 16] : 0.f;
        unsigned short h = f2bf(xv);
        float r = xv - bf2f(h);
        unsigned short l = f2bf(r);
        float r2 = r - bf2f(l);
        Bh[j] = (short)h; Bl[j] = (short)l; Bll[j] = (short)f2bf(r2);
      }
#pragma unroll
      for (int mt = 0; mt < 4; ++mt) {
        f32x4 a = acc[tile][mt];
        a = __builtin_amdgcn_mfma_f32_16x16x32_bf16(A[0][mt], Bh, a, 0, 0, 0);
        a = __builtin_amdgcn_mfma_f32_16x16x32_bf16(A[1][mt], Bh, a, 0, 0, 0);
        a = __builtin_amdgcn_mfma_f32_16x16x32_bf16(A[2][mt], Bh, a, 0, 0, 0);
        a = __builtin_amdgcn_mfma_f32_16x16x32_bf16(A[0][mt], Bl, a, 0, 0, 0);
        a = __builtin_amdgcn_mfma_f32_16x16x32_bf16(A[1][mt], Bl, a, 0, 0, 0);
        a = __builtin_amdgcn_mfma_f32_16x16x32_bf16(A[2][mt], Bl, a, 0, 0, 0);
        a = __builtin_amdgcn_mfma_f32_16x16x32_bf16(A[0][mt], Bll, a, 0, 0, 0);
        a = __builtin_amdgcn_mfma_f32_16x16x32_bf16(A[1][mt], Bll, a, 0, 0, 0);
        acc[tile][mt] = a;
      }
    }
#pragma unroll
    for (int tile = 0; tile < 2; ++tile)
#pragma unroll
      for (int mt = 0; mt < 4; ++mt)
#pragma unroll
        for (int reg = 0; reg < 4; ++reg) {
          float val = acc[tile][mt][reg];
          s1[mt][reg] += val; s2[mt][reg] = fmaf(val, val, s2[mt][reg]);
        }
  }
#pragma unroll
  for (int mt = 0; mt < 4; ++mt)
#pragma unroll
    for (int reg = 0; reg < 4; ++reg) {
      float a1 = s1[mt][reg], a2 = s2[mt][reg];
#pragma unroll
      for (int off = 1; off < 16; off <<= 1) { a1 += __shfl_xor(a1, off); a2 += __shfl_xor(a2, off); }
      if (xl == 0) {
        int co = mt * 16 + q * 4 + reg;
        atomicAdd(&s1p[sp * 128 + co], a1);
        atomicAdd(&s1p[sp * 128 + 64 + co], a2);
      }
    }
}

// ---- conv1 pass 2 (MFMA im2col): fused conv+BN+LIF+pool -> pool1. Wave = row; v in regs. ----
__global__ __launch_bounds__(256) void conv1_fused_mfma(const float* __restrict__ x,
    const unsigned short* __restrict__ A1, const float* __restrict__ scale,
    const float* __restrict__ shift, unsigned short* __restrict__ pool1) {
  int b = blockIdx.x >> 3, yq = blockIdx.x & 7;
  int y0 = yq * 4;
  int tid = threadIdx.x, wave = tid >> 6, lane = tid & 63;
  int xl = lane & 15, q = lane >> 4;
  __shared__ float xs[648];
  __shared__ unsigned short shout[4 * 16 * 72];   // [w 4][pp 16][co 64], pp-stride 72
  short8 A[3][4];
#pragma unroll
  for (int mt = 0; mt < 4; ++mt) {
    int aoff = (mt * 16 + xl) * 32 + q * 8;
    A[0][mt] = *(const short8*)(A1 + aoff);
    A[1][mt] = *(const short8*)(A1 + 2048 + aoff);
    A[2][mt] = *(const short8*)(A1 + 4096 + aoff);
  }
  int cb[8]; bool vld[8];
#pragma unroll
  for (int j = 0; j < 8; ++j) {
    int k = q * 8 + j;
    int tap = k / 3, ci = k - tap * 3;
    int dy = tap / 3, dx = tap - dy * 3;
    vld[j] = (k < 27);
    cb[j] = ci * 216 + (wave + dy) * 36 + dx + xl;
  }
  float scr[4][4], shr[4][4];
#pragma unroll
  for (int mt = 0; mt < 4; ++mt)
#pragma unroll
    for (int reg = 0; reg < 4; ++reg) {
      int co = mt * 16 + q * 4 + reg;
      scr[mt][reg] = scale[co]; shr[mt][reg] = shift[co];
    }
  float v[2][4][4];
#pragma unroll
  for (int tile = 0; tile < 2; ++tile)
#pragma unroll
    for (int mt = 0; mt < 4; ++mt)
#pragma unroll
      for (int reg = 0; reg < 4; ++reg) v[tile][mt][reg] = 0.f;

#pragma unroll 1
  for (int t = 0; t < 8; ++t) {
    int tb = t * 128 + b;
    const float* xb = x + tb * 3072;
    __syncthreads();   // xs + shout free from previous t
    for (int i = tid; i < 648; i += 256) {
      int ci = i / 216, r1 = i - ci * 216;
      int rr = r1 / 36, c = r1 - rr * 36;
      int gy = y0 - 1 + rr, gx = c - 1;
      xs[i] = ((unsigned)gy < 32u && (unsigned)gx < 32u) ? xb[(ci * 32 + gy) * 32 + gx] : 0.f;
    }
    __syncthreads();
    f32x4 acc[2][4];
#pragma unroll
    for (int tile = 0; tile < 2; ++tile)
#pragma unroll
      for (int mt = 0; mt < 4; ++mt) acc[tile][mt] = (f32x4){0.f, 0.f, 0.f, 0.f};
#pragma unroll
    for (int tile = 0; tile < 2; ++tile) {
      short8 Bh = (short8){0,0,0,0,0,0,0,0};
      short8 Bl = (short8){0,0,0,0,0,0,0,0};
      short8 Bll = (short8){0,0,0,0,0,0,0,0};
#pragma unroll
      for (int j = 0; j < 8; ++j) {
        float xv = vld[j] ? xs[cb[j] + tile * 16] : 0.f;
        unsigned short h = f2bf(xv);
        float r = xv - bf2f(h);
        unsigned short l = f2bf(r);
        float r2 = r - bf2f(l);
        Bh[j] = (short)h; Bl[j] = (short)l; Bll[j] = (short)f2bf(r2);
      }
#pragma unroll
      for (int mt = 0; mt < 4; ++mt) {
        f32x4 a = acc[tile][mt];
        a = __builtin_amdgcn_mfma_f32_16x16x32_bf16(A[0][mt], Bh, a, 0, 0, 0);
        a = __builtin_amdgcn_mfma_f32_16x16x32_bf16(A[1][mt], Bh, a, 0, 0, 0);
        a = __builtin_amdgcn_mfma_f32_16x16x32_bf16(A[2][mt], Bh, a, 0, 0, 0);
        a = __builtin_amdgcn_mfma_f32_16x16x32_bf16(A[0][mt], Bl, a, 0, 0, 0);
        a = __builtin_amdgcn_mfma_f32_16x16x32_bf16(A[1][mt], Bl, a, 0, 0, 0);
        a = __builtin_amdgcn_mfma_f32_16x16x32_bf16(A[2][mt], Bl, a, 0, 0, 0);
        a = __builtin_amdgcn_mfma_f32_16x16x32_bf16(A[0][mt], Bll, a, 0, 0, 0);
        a = __builtin_amdgcn_mfma_f32_16x16x32_bf16(A[1][mt], Bll, a, 0, 0, 0);
        acc[tile][mt] = a;
      }
    }
    // epilogue: BN + LIF + horizontal pool; lane parity picks tile; write [w][pp][co]
#pragma unroll
    for (int mt = 0; mt < 4; ++mt)
#pragma unroll
      for (int rp = 0; rp < 2; ++rp) {
        float hp[2][2];
#pragma unroll
        for (int tile = 0; tile < 2; ++tile)
#pragma unroll
          for (int e = 0; e < 2; ++e) {
            int reg = rp * 2 + e;
            float xv = fmaf(acc[tile][mt][reg], scr[mt][reg], shr[mt][reg]);
            float spk;
            LIF_STEP(v[tile][mt][reg], xv, spk);
            hp[tile][e] = spk + __shfl_xor(spk, 1);
          }
        int tw = xl & 1;
        float h0 = tw ? hp[1][0] : hp[0][0];
        float h1 = tw ? hp[1][1] : hp[0][1];
        unsigned u = (unsigned)f2bf(h0) | ((unsigned)f2bf(h1) << 16);
        int pp = tw * 8 + (xl >> 1);
        *(unsigned*)&shout[(wave * 16 + pp) * 72 + mt * 16 + q * 4 + rp * 2] = u;
      }
    __syncthreads();
    // vertical pool + copy-out: pool1 [tb][cg][py][px][ci_l 8]
    {
      int cg = tid >> 5, py_l = (tid >> 4) & 1, px = tid & 15;
      uint4 ua = *(const uint4*)&shout[((2 * py_l) * 16 + px) * 72 + cg * 8];
      uint4 ub = *(const uint4*)&shout[((2 * py_l + 1) * 16 + px) * 72 + cg * 8];
      const unsigned* pa = (const unsigned*)&ua;
      const unsigned* pb = (const unsigned*)&ub;
      unsigned o[4];
#pragma unroll
      for (int e = 0; e < 4; ++e) {
        float a0 = bf2f((unsigned short)(pa[e] & 0xffffu)), a1 = bf2f((unsigned short)(pa[e] >> 16));
        float b0 = bf2f((unsigned short)(pb[e] & 0xffffu)), b1 = bf2f((unsigned short)(pb[e] >> 16));
        o[e] = (unsigned)f2bf(0.25f * (a0 + b0)) | ((unsigned)f2bf(0.25f * (a1 + b1)) << 16);
      }
      int py = yq * 2 + py_l;
      *(uint4*)(pool1 + (size_t)tb * 16384 + cg * 2048 + (py * 16 + px) * 8) =
          make_uint4(o[0], o[1], o[2], o[3]);
    }
  }
}

// ---- conv2 (MFMA, single pass): stats + fp32 preact store. (validated R8) ----
__global__ __launch_bounds__(256, 2) void conv2_store_mfma(const unsigned short* __restrict__ pool1,
    const unsigned short* __restrict__ A2, float* __restrict__ preact, float* __restrict__ s2p) {
  int bx = blockIdx.x;
  int tb = bx >> 2, q4 = bx & 3;
  int sp = bx & 63;
  __shared__ unsigned short simg[6 * 8 * 18 * 8];
  int tid = threadIdx.x;
  const unsigned* src = (const unsigned*)(pool1 + (size_t)tb * 16384);
  unsigned* dstw = (unsigned*)simg;
  for (int i = tid; i < 3456; i += 256) {
    int cp = i & 3, rest = i >> 2;
    int jj = rest / 18, xx = rest - jj * 18;
    int cg = jj & 7, row_l = jj >> 3;
    int yi = q4 * 4 - 1 + row_l, gx = xx - 1;
    unsigned val = 0u;
    if ((unsigned)yi < 16u && (unsigned)gx < 16u)
      val = src[cg * 1024 + yi * 64 + gx * 4 + cp];
    dstw[i] = val;
  }
  __syncthreads();

  int wave = tid >> 6, lane = tid & 63;
  int xl = lane & 15, q = lane >> 4;
  int m0 = wave * 32;
  f32x4 acc[2][4];
#pragma unroll
  for (int mt = 0; mt < 2; ++mt)
#pragma unroll
    for (int yl = 0; yl < 4; ++yl) acc[mt][yl] = (f32x4){0.f, 0.f, 0.f, 0.f};

  short8 a_cur[2][3];
#pragma unroll
  for (int mt = 0; mt < 2; ++mt) {
    int aoff = ((m0 + mt * 16 + xl) * 4 + q) * 8;
    a_cur[mt][0] = *(const short8*)(A2 + aoff);
    a_cur[mt][1] = *(const short8*)(A2 + 73728 + aoff);
    a_cur[mt][2] = *(const short8*)(A2 + 147456 + aoff);
  }

#pragma unroll 1
  for (int kc = 0; kc < 18; ++kc) {
    short8 a_nxt[2][3];
    if (kc < 17) {
#pragma unroll
      for (int mt = 0; mt < 2; ++mt) {
        int aoff = (((kc + 1) * 128 + m0 + mt * 16 + xl) * 4 + q) * 8;
        a_nxt[mt][0] = *(const short8*)(A2 + aoff);
        a_nxt[mt][1] = *(const short8*)(A2 + 73728 + aoff);
        a_nxt[mt][2] = *(const short8*)(A2 + 147456 + aoff);
      }
    } else {
#pragma unroll
      for (int mt = 0; mt < 2; ++mt)
#pragma unroll
        for (int sv = 0; sv < 3; ++sv) a_nxt[mt][sv] = a_cur[mt][sv];
    }
    int tap = kc >> 1;
    int dy = tap / 3, dx = tap - dy * 3;
    int cgq = (kc & 1) * 4 + q;
#pragma unroll
    for (int yl = 0; yl < 4; ++yl) {
      int baddr = (((yl + dy) * 8 + cgq) * 18 + (xl + dx)) * 8;
      short8 bb = *(const short8*)(simg + baddr);
#pragma unroll
      for (int mt = 0; mt < 2; ++mt) {
        acc[mt][yl] = __builtin_amdgcn_mfma_f32_16x16x32_bf16(a_cur[mt][0], bb, acc[mt][yl], 0, 0, 0);
        acc[mt][yl] = __builtin_amdgcn_mfma_f32_16x16x32_bf16(a_cur[mt][1], bb, acc[mt][yl], 0, 0, 0);
        acc[mt][yl] = __builtin_amdgcn_mfma_f32_16x16x32_bf16(a_cur[mt][2], bb, acc[mt][yl], 0, 0, 0);
      }
    }
#pragma unroll
    for (int mt = 0; mt < 2; ++mt)
#pragma unroll
      for (int sv = 0; sv < 3; ++sv) a_cur[mt][sv] = a_nxt[mt][sv];
  }

  float* pre = preact + (size_t)tb * 32768;
#pragma unroll
  for (int mt = 0; mt < 2; ++mt)
#pragma unroll
    for (int reg = 0; reg < 4; ++reg) {
      int co = m0 + mt * 16 + q * 4 + reg;
      float s1 = 0.f, s2 = 0.f;
#pragma unroll
      for (int yl = 0; yl < 4; ++yl) {
        float val = acc[mt][yl][reg];
        int row = q4 * 4 + yl;
        pre[(row * 128 + co) * 16 + xl] = val;
        s1 += val; s2 = fmaf(val, val, s2);
      }
#pragma unroll
      for (int off = 1; off < 16; off <<= 1) {
        s1 += __shfl_xor(s1, off); s2 += __shfl_xor(s2, off);
      }
      if (xl == 0) {
        atomicAdd(&s2p[sp * 256 + co], s1);
        atomicAdd(&s2p[sp * 256 + 128 + co], s2);
      }
    }
}

// ---- BN2 + LIF + pool over stored preact. (validated R8) ----
__global__ __launch_bounds__(256) void bn2_lif_pool(const float* __restrict__ pre,
    const float* __restrict__ scale, const float* __restrict__ shift,
    unsigned short* __restrict__ pool2) {
  int b = blockIdx.x >> 2, q4 = blockIdx.x & 3;
  int tid = threadIdx.x;
  int co = tid >> 1, half = tid & 1;
  __shared__ unsigned short shout[16 * 136];
  float sc = scale[co], sh = shift[co];
  float v[2][4][4];
#pragma unroll
  for (int a = 0; a < 2; ++a)
#pragma unroll
    for (int p = 0; p < 4; ++p)
#pragma unroll
      for (int e = 0; e < 4; ++e) v[a][p][e] = 0.f;

#pragma unroll 1
  for (int t = 0; t < 8; ++t) {
    const float* base = pre + ((size_t)((t * 128 + b) * 16 + q4 * 4)) * 2048 + co * 16 + half * 8;
    __syncthreads();
#pragma unroll
    for (int py_l = 0; py_l < 2; ++py_l) {
      float4 r0a = *(const float4*)(base + (py_l * 2) * 2048);
      float4 r0b = *(const float4*)(base + (py_l * 2) * 2048 + 4);
      float4 r1a = *(const float4*)(base + (py_l * 2 + 1) * 2048);
      float4 r1b = *(const float4*)(base + (py_l * 2 + 1) * 2048 + 4);
      float p00[4] = {r0a.x, r0a.z, r0b.x, r0b.z};
      float p01[4] = {r0a.y, r0a.w, r0b.y, r0b.w};
      float p10[4] = {r1a.x, r1a.z, r1b.x, r1b.z};
      float p11[4] = {r1a.y, r1a.w, r1b.y, r1b.w};
#pragma unroll
      for (int p = 0; p < 4; ++p) {
        float s00, s01, s10, s11, xv;
        xv = fmaf(p00[p], sc, sh); LIF_STEP(v[py_l][p][0], xv, s00);
        xv = fmaf(p01[p], sc, sh); LIF_STEP(v[py_l][p][1], xv, s01);
        xv = fmaf(p10[p], sc, sh); LIF_STEP(v[py_l][p][2], xv, s10);
        xv = fmaf(p11[p], sc, sh); LIF_STEP(v[py_l][p][3], xv, s11);
        int s_l = py_l * 8 + half * 4 + p;
        shout[s_l * 136 + co] = f2bf(0.25f * (s00 + s01 + s10 + s11));
      }
    }
    __syncthreads();
    {
      int s_l = tid >> 4, ci8 = (tid & 15) * 8;
      uint4 vv = *(const uint4*)&shout[s_l * 136 + ci8];
      *(uint4*)(pool2 + ((size_t)(t * 128 + b) * 64 + q4 * 16 + s_l) * 128 + ci8) = vv;
    }
  }
}

// ---- fc1 (MFMA): partial[kb][o 256][tb 1024], split-K=16, no atomics. (validated) ----
__global__ __launch_bounds__(256, 2) void fc1_mfma(const unsigned short* __restrict__ pool2,
    const unsigned short* __restrict__ B1, float* __restrict__ partial) {
  int bx = blockIdx.x;
  int t_o = bx & 1, tbt = (bx >> 1) & 15, kb = bx >> 5;
  int tid = threadIdx.x, wave = tid >> 6, lane = tid & 63;
  int xl = lane & 15, q = lane >> 4;
  int m0 = t_o * 128 + wave * 32;
  int n0 = tbt * 64;
  __shared__ unsigned short sB[64 * 42];
  f32x4 acc[2][4];
#pragma unroll
  for (int mt = 0; mt < 2; ++mt)
#pragma unroll
    for (int nt = 0; nt < 4; ++nt) acc[mt][nt] = (f32x4){0.f, 0.f, 0.f, 0.f};

#pragma unroll 1
  for (int kc0 = 0; kc0 < 16; ++kc0) {
    int kc = kb * 16 + kc0;
    __syncthreads();
    {
      int tb_l = tid >> 2, kq = tid & 3;
      uint4 vv = *(const uint4*)(pool2 + (size_t)(n0 + tb_l) * 8192 + kc * 32 + kq * 8);
      *(uint4*)(sB + tb_l * 42 + kq * 8) = vv;
    }
    __syncthreads();
    short8 a[2][3];
#pragma unroll
    for (int mt = 0; mt < 2; ++mt) {
      int aoff = ((kc * 256 + m0 + mt * 16 + xl) * 4 + q) * 8;
      a[mt][0] = *(const short8*)(B1 + aoff);
      a[mt][1] = *(const short8*)(B1 + 2097152 + aoff);
      a[mt][2] = *(const short8*)(B1 + 4194304 + aoff);
    }
#pragma unroll
    for (int nt = 0; nt < 4; ++nt) {
      short8 bb = *(const short8*)(sB + (nt * 16 + xl) * 42 + q * 8);
#pragma unroll
      for (int mt = 0; mt < 2; ++mt) {
        acc[mt][nt] = __builtin_amdgcn_mfma_f32_16x16x32_bf16(a[mt][0], bb, acc[mt][nt], 0, 0, 0);
        acc[mt][nt] = __builtin_amdgcn_mfma_f32_16x16x32_bf16(a[mt][1], bb, acc[mt][nt], 0, 0, 0);
        acc[mt][nt] = __builtin_amdgcn_mfma_f32_16x16x32_bf16(a[mt][2], bb, acc[mt][nt], 0, 0, 0);
      }
    }
  }
#pragma unroll
  for (int mt = 0; mt < 2; ++mt)
#pragma unroll
    for (int nt = 0; nt < 4; ++nt)
#pragma unroll
      for (int reg = 0; reg < 4; ++reg) {
        int o = m0 + mt * 16 + q * 4 + reg;
        partial[((size_t)kb * 256 + o) * 1024 + n0 + nt * 16 + xl] = acc[mt][nt][reg];
      }
}

// ---- reduce partials + LIF -> fc1 spikes [t][b][o]. ----
__global__ __launch_bounds__(256) void reduce_lif(const float* __restrict__ partial, float* __restrict__ fs) {
  int idx = blockIdx.x * 256 + threadIdx.x;
  int o = idx >> 7, b = idx & 127;
  float v = 0.f;
#pragma unroll 1
  for (int t = 0; t < 8; ++t) {
    float xv = 0.f;
#pragma unroll
    for (int kb = 0; kb < 16; ++kb)
      xv += partial[((size_t)kb * 256 + o) * 1024 + t * 128 + b];
    float s;
    LIF_STEP(v, xv, s);
    fs[t * 32768 + b * 256 + o] = s;
  }
}

__global__ __launch_bounds__(256) void fc2_kernel(const float* __restrict__ fs, const float* __restrict__ w,
                                                  const float* __restrict__ bias, float* __restrict__ outp) {
  int tb = blockIdx.x;
  __shared__ float sv[256];
  int tid = threadIdx.x;
  sv[tid] = fs[tb * 256 + tid];
  __syncthreads();
  if (tid < 10) {
    float a = bias[tid];
    const float* wr = w + tid * 256;
#pragma unroll 8
    for (int o = 0; o < 256; ++o) a = fmaf(sv[o], wr[o], a);
    outp[tb * 10 + tid] = a;
  }
}

extern "C" void kernel_launch(void* const* d_in, const int* in_sizes, int n_in,
                              void* d_out, int out_size, void* d_ws, size_t ws_size,
                              hipStream_t stream) {
  (void)in_sizes; (void)n_in; (void)out_size; (void)ws_size;
  const float* x_seq   = (const float*)d_in[0];
  const float* conv1_w = (const float*)d_in[1];
  const float* bn1_g   = (const float*)d_in[2];
  const float* bn1_b   = (const float*)d_in[3];
  const float* conv2_w = (const float*)d_in[4];
  const float* bn2_g   = (const float*)d_in[5];
  const float* bn2_b   = (const float*)d_in[6];
  const float* fc1_w   = (const float*)d_in[7];
  const float* fc2_w   = (const float*)d_in[8];
  const float* fc2_b   = (const float*)d_in[9];
  float* out = (float*)d_out;
  float* ws  = (float*)d_ws;

  unsigned short* pool1 = (unsigned short*)(ws + OFF_POOL1);
  float* fc1_part = ws + OFF_POOL1;              // pool1 dead after conv2_store
  unsigned short* pool2 = (unsigned short*)(ws + OFF_POOL2);
  float* preact  = ws + OFF_PRE;
  float* fc1_s   = ws + OFF_FC1S;
  unsigned short* A2 = (unsigned short*)(ws + OFF_A2);
  unsigned short* B1 = (unsigned short*)(ws + OFF_B1);
  unsigned short* A1 = (unsigned short*)(ws + OFF_A1);
  float* st      = ws + OFF_STATS;
  float* s1p    = st;            // [64 sp][2][64]
  float* s2p    = st + 8192;     // [64 sp][2][128]
  float* bn1_sc = st + 24576;  float* bn1_sh = st + 24640;
  float* bn2_sc = st + 24704;  float* bn2_sh = st + 24832;

  zero_kernel<<<96, 256, 0, stream>>>(st, ZERO_STATS);
  prep_w1<<<8, 256, 0, stream>>>(conv1_w, A1);
  prep_w2<<<288, 256, 0, stream>>>(conv2_w, A2);
  prep_b1<<<128, 256, 0, stream>>>(fc1_w, B1);
  conv1_pass1_mfma<<<1024, 256, 0, stream>>>(x_seq, A1, s1p);
  finalize_bn1<<<1, 64, 0, stream>>>(s1p, bn1_g, bn1_b, bn1_sc, bn1_sh, 1.0f / 1048576.0f);
  conv1_fused_mfma<<<1024, 256, 0, stream>>>(x_seq, A1, bn1_sc, bn1_sh, pool1);
  conv2_store_mfma<<<4096, 256, 0, stream>>>(pool1, A2, preact, s2p);
  finalize_bn2<<<1, 128, 0, stream>>>(s2p, bn2_g, bn2_b, bn2_sc, bn2_sh, 1.0f / 262144.0f);
  bn2_lif_pool<<<512, 256, 0, stream>>>(preact, bn2_sc, bn2_sh, pool2);
  fc1_mfma<<<512, 256, 0, stream>>>(pool2, B1, fc1_part);
  reduce_lif<<<128, 256, 0, stream>>>(fc1_part, fc1_s);
  fc2_kernel<<<1024, 256, 0, stream>>>(fc1_s, fc2_w, fc2_b, out);
}

// Round 10
// 402.542 us; speedup vs baseline: 1.6020x; 1.0355x over previous
//
#include <hip/hip_runtime.h>

// SNN forward — all three heavy ops (conv1, conv2, fc1) on MFMA bf16.
// R10: conv2_store kc-loop unrolled x2 with A-frag register rotation (no copies);
//      bn2_lif_pool regridded 512->1024 (block = pool row); prep_b1 grid 384.

#define LIF_STEP(vv, xx, ss) do { \
    vv = fmaf((xx) - vv, 0.5f, vv); \
    ss = (vv >= 1.0f) ? 1.0f : 0.0f; \
    vv = (vv >= 1.0f) ? 0.0f : vv; \
  } while (0)

typedef __attribute__((ext_vector_type(8))) short short8;
typedef __attribute__((ext_vector_type(4))) float f32x4;

__device__ __forceinline__ float bf2f(unsigned short u) {
  return __uint_as_float(((unsigned)u) << 16);
}
__device__ __forceinline__ unsigned short f2bf(float f) {
  return (unsigned short)(__float_as_uint(f) >> 16);  // truncation split
}

// ---- workspace layout (float-slot offsets) ----
// pool1 bf16 [1024 tb][8 cg][16 py][16 px][8 ci_l] = 16,777,216 u16 (8,388,608 f)
//   (reused AFTER conv2_store as fc1 partials f32 [16 kb][256 o][1024 tb])
// pool2 bf16 [1024 tb][64 s][128 ci] = 8,388,608 u16 (4,194,304 f)
// preact f32 [1024 tb][16 row][128 co][16 col] = 33,554,432 f
#define OFF_POOL1   0u
#define OFF_POOL2   8388608u
#define OFF_PRE     12582912u
#define OFF_STATS   46137344u   // f32 24,960
#define OFF_FC1S    46162304u   // f32 262,144
#define OFF_A2      46424448u   // bf16 3x[18 kc][128 co][4 q][8 j]
#define OFF_B1      46535040u   // bf16 3x[256 kc][256 o][4 q][8 j]
#define OFF_A1      49680768u   // bf16 3x[64 co][32 k]
// total 49,683,840 floats = 198.7 MB
// stats sublayout: s1p[64 sp][2][64] | s2p[64 sp][2][128] | bn1_sc/sh(64) bn2_sc/sh(128)
#define ZERO_STATS 24576u

__global__ __launch_bounds__(256) void zero_kernel(float* __restrict__ p, unsigned n) {
  unsigned i = blockIdx.x * 256u + threadIdx.x;
  if (i < n) p[i] = 0.0f;
}

// conv1_w [64 co][3 ci][3 ky][3 kx] -> A1[sv][co][k], k = tap*3+ci, k>=27 zero
__global__ __launch_bounds__(256) void prep_w1(const float* __restrict__ w, unsigned short* __restrict__ A1) {
  int i = blockIdx.x * 256 + threadIdx.x;
  if (i >= 2048) return;
  int co = i >> 5, k = i & 31;
  float wv = 0.f;
  if (k < 27) {
    int tap = k / 3, ci = k - tap * 3;
    wv = w[co * 27 + ci * 9 + tap];
  }
  unsigned short hi = f2bf(wv);
  float rem = wv - bf2f(hi);
  unsigned short lo = f2bf(rem);
  float rem2 = rem - bf2f(lo);
  A1[i] = hi;
  A1[2048 + i] = lo;
  A1[4096 + i] = f2bf(rem2);
}

// conv2_w -> 3-way bf16 split in MFMA A-frag order (validated)
__global__ __launch_bounds__(256) void prep_w2(const float* __restrict__ w, unsigned short* __restrict__ A2) {
  int i = blockIdx.x * 256 + threadIdx.x;
  if (i >= 73728) return;
  int co = i / 576, r = i - co * 576;
  int ci = r / 9, t9 = r - ci * 9;
  int k = t9 * 64 + ci;
  int kc = k >> 5, q = (k >> 3) & 3, j = k & 7;
  int off = ((kc * 128 + co) * 4 + q) * 8 + j;
  float wv = w[i];
  unsigned short hi = f2bf(wv);
  float rem = wv - bf2f(hi);
  unsigned short lo = f2bf(rem);
  float rem2 = rem - bf2f(lo);
  A2[off] = hi;
  A2[73728 + off] = lo;
  A2[147456 + off] = f2bf(rem2);
}

// fc1_w -> 3-way split via LDS transpose; R10: one sv per block (grid 384)
__global__ __launch_bounds__(256) void prep_b1(const float* __restrict__ w, unsigned short* __restrict__ B1) {
  __shared__ unsigned short sh[2][8192];
  int blk = blockIdx.x;        // 384 = sv*128 + opair
  int sv = blk >> 7, opair = blk & 127;
  int tid = threadIdx.x;
  for (int o_l = 0; o_l < 2; ++o_l) {
    for (int it = 0; it < 32; ++it) {
      int korig = tid + 256 * it;
      float wv = w[(size_t)(opair * 2 + o_l) * 8192 + korig];
      unsigned short hi = f2bf(wv);
      float rem = wv - bf2f(hi);
      unsigned short lo = f2bf(rem);
      unsigned short pc = (sv == 0) ? hi : (sv == 1) ? lo : f2bf(rem - bf2f(lo));
      int k = (korig & 63) * 128 + (korig >> 6);
      sh[o_l][k] = pc;
    }
  }
  __syncthreads();
  unsigned short* outp = B1 + (size_t)sv * 2097152;
  for (int it = 0; it < 64; ++it) {
    int idx = tid + 256 * it;
    int kc = idx >> 6, r = idx & 63;
    int o_l = r >> 5, m = r & 31;
    outp[kc * 8192 + opair * 64 + r] = sh[o_l][kc * 32 + m];
  }
}

// layer-1 finalize: reduce 64-way spread partials [sp][2][64]
__global__ void finalize_bn1(const float* __restrict__ s1p,
                             const float* __restrict__ g, const float* __restrict__ b,
                             float* __restrict__ scale, float* __restrict__ shift, float inv_n) {
  int c = threadIdx.x;
  float s1 = 0.f, s2 = 0.f;
#pragma unroll 8
  for (int sp = 0; sp < 64; ++sp) {
    s1 += s1p[sp * 128 + c];
    s2 += s1p[sp * 128 + 64 + c];
  }
  float mean = s1 * inv_n;
  float var = fmaxf(s2 * inv_n - mean * mean, 0.0f);
  float rstd = rsqrtf(var + 1e-5f);
  float sc = g[c] * rstd;
  scale[c] = sc;
  shift[c] = fmaf(-mean, sc, b[c]);
}

// layer-2 finalize: reduce 64-way spread partials [sp][2][128]
__global__ void finalize_bn2(const float* __restrict__ s2p,
                             const float* __restrict__ g, const float* __restrict__ b,
                             float* __restrict__ scale, float* __restrict__ shift, float inv_n) {
  int c = threadIdx.x;
  float s1 = 0.f, s2 = 0.f;
#pragma unroll 8
  for (int sp = 0; sp < 64; ++sp) {
    s1 += s2p[sp * 256 + c];
    s2 += s2p[sp * 256 + 128 + c];
  }
  float mean = s1 * inv_n;
  float var = fmaxf(s2 * inv_n - mean * mean, 0.0f);
  float rstd = rsqrtf(var + 1e-5f);
  float sc = g[c] * rstd;
  scale[c] = sc;
  shift[c] = fmaf(-mean, sc, b[c]);
}

// ---- conv1 pass 1 (MFMA im2col): stats only. (validated R9) ----
__global__ __launch_bounds__(256) void conv1_pass1_mfma(const float* __restrict__ x,
    const unsigned short* __restrict__ A1, float* __restrict__ s1p) {
  int b = blockIdx.x >> 3, yq = blockIdx.x & 7;
  int y0 = yq * 4;
  int sp = blockIdx.x & 63;
  int tid = threadIdx.x, wave = tid >> 6, lane = tid & 63;
  int xl = lane & 15, q = lane >> 4;
  __shared__ float xs[648];
  short8 A[3][4];
#pragma unroll
  for (int mt = 0; mt < 4; ++mt) {
    int aoff = (mt * 16 + xl) * 32 + q * 8;
    A[0][mt] = *(const short8*)(A1 + aoff);
    A[1][mt] = *(const short8*)(A1 + 2048 + aoff);
    A[2][mt] = *(const short8*)(A1 + 4096 + aoff);
  }
  int cb[8]; bool vld[8];
#pragma unroll
  for (int j = 0; j < 8; ++j) {
    int k = q * 8 + j;
    int tap = k / 3, ci = k - tap * 3;
    int dy = tap / 3, dx = tap - dy * 3;
    vld[j] = (k < 27);
    cb[j] = ci * 216 + (wave + dy) * 36 + dx + xl;
  }
  float s1[4][4], s2[4][4];
#pragma unroll
  for (int mt = 0; mt < 4; ++mt)
#pragma unroll
    for (int reg = 0; reg < 4; ++reg) { s1[mt][reg] = 0.f; s2[mt][reg] = 0.f; }

#pragma unroll 1
  for (int t = 0; t < 8; ++t) {
    int tb = t * 128 + b;
    const float* xb = x + tb * 3072;
    __syncthreads();
    for (int i = tid; i < 648; i += 256) {
      int ci = i / 216, r1 = i - ci * 216;
      int rr = r1 / 36, c = r1 - rr * 36;
      int gy = y0 - 1 + rr, gx = c - 1;
      xs[i] = ((unsigned)gy < 32u && (unsigned)gx < 32u) ? xb[(ci * 32 + gy) * 32 + gx] : 0.f;
    }
    __syncthreads();
    f32x4 acc[2][4];
#pragma unroll
    for (int tile = 0; tile < 2; ++tile)
#pragma unroll
      for (int mt = 0; mt < 4; ++mt) acc[tile][mt] = (f32x4){0.f, 0.f, 0.f, 0.f};
#pragma unroll
    for (int tile = 0; tile < 2; ++tile) {
      short8 Bh = (short8){0,0,0,0,0,0,0,0};
      short8 Bl = (short8){0,0,0,0,0,0,0,0};
      short8 Bll = (short8){0,0,0,0,0,0,0,0};
#pragma unroll
      for (int j = 0; j < 8; ++j) {
        float xv = vld[j] ? xs[cb[j] + tile * 16] : 0.f;
        unsigned short h = f2bf(xv);
        float r = xv - bf2f(h);
        unsigned short l = f2bf(r);
        float r2 = r - bf2f(l);
        Bh[j] = (short)h; Bl[j] = (short)l; Bll[j] = (short)f2bf(r2);
      }
#pragma unroll
      for (int mt = 0; mt < 4; ++mt) {
        f32x4 a = acc[tile][mt];
        a = __builtin_amdgcn_mfma_f32_16x16x32_bf16(A[0][mt], Bh, a, 0, 0, 0);
        a = __builtin_amdgcn_mfma_f32_16x16x32_bf16(A[1][mt], Bh, a, 0, 0, 0);
        a = __builtin_amdgcn_mfma_f32_16x16x32_bf16(A[2][mt], Bh, a, 0, 0, 0);
        a = __builtin_amdgcn_mfma_f32_16x16x32_bf16(A[0][mt], Bl, a, 0, 0, 0);
        a = __builtin_amdgcn_mfma_f32_16x16x32_bf16(A[1][mt], Bl, a, 0, 0, 0);
        a = __builtin_amdgcn_mfma_f32_16x16x32_bf16(A[2][mt], Bl, a, 0, 0, 0);
        a = __builtin_amdgcn_mfma_f32_16x16x32_bf16(A[0][mt], Bll, a, 0, 0, 0);
        a = __builtin_amdgcn_mfma_f32_16x16x32_bf16(A[1][mt], Bll, a, 0, 0, 0);
        acc[tile][mt] = a;
      }
    }
#pragma unroll
    for (int tile = 0; tile < 2; ++tile)
#pragma unroll
      for (int mt = 0; mt < 4; ++mt)
#pragma unroll
        for (int reg = 0; reg < 4; ++reg) {
          float val = acc[tile][mt][reg];
          s1[mt][reg] += val; s2[mt][reg] = fmaf(val, val, s2[mt][reg]);
        }
  }
#pragma unroll
  for (int mt = 0; mt < 4; ++mt)
#pragma unroll
    for (int reg = 0; reg < 4; ++reg) {
      float a1 = s1[mt][reg], a2 = s2[mt][reg];
#pragma unroll
      for (int off = 1; off < 16; off <<= 1) { a1 += __shfl_xor(a1, off); a2 += __shfl_xor(a2, off); }
      if (xl == 0) {
        int co = mt * 16 + q * 4 + reg;
        atomicAdd(&s1p[sp * 128 + co], a1);
        atomicAdd(&s1p[sp * 128 + 64 + co], a2);
      }
    }
}

// ---- conv1 pass 2 (MFMA im2col): fused conv+BN+LIF+pool -> pool1. (validated R9) ----
__global__ __launch_bounds__(256) void conv1_fused_mfma(const float* __restrict__ x,
    const unsigned short* __restrict__ A1, const float* __restrict__ scale,
    const float* __restrict__ shift, unsigned short* __restrict__ pool1) {
  int b = blockIdx.x >> 3, yq = blockIdx.x & 7;
  int y0 = yq * 4;
  int tid = threadIdx.x, wave = tid >> 6, lane = tid & 63;
  int xl = lane & 15, q = lane >> 4;
  __shared__ float xs[648];
  __shared__ unsigned short shout[4 * 16 * 72];
  short8 A[3][4];
#pragma unroll
  for (int mt = 0; mt < 4; ++mt) {
    int aoff = (mt * 16 + xl) * 32 + q * 8;
    A[0][mt] = *(const short8*)(A1 + aoff);
    A[1][mt] = *(const short8*)(A1 + 2048 + aoff);
    A[2][mt] = *(const short8*)(A1 + 4096 + aoff);
  }
  int cb[8]; bool vld[8];
#pragma unroll
  for (int j = 0; j < 8; ++j) {
    int k = q * 8 + j;
    int tap = k / 3, ci = k - tap * 3;
    int dy = tap / 3, dx = tap - dy * 3;
    vld[j] = (k < 27);
    cb[j] = ci * 216 + (wave + dy) * 36 + dx + xl;
  }
  float scr[4][4], shr[4][4];
#pragma unroll
  for (int mt = 0; mt < 4; ++mt)
#pragma unroll
    for (int reg = 0; reg < 4; ++reg) {
      int co = mt * 16 + q * 4 + reg;
      scr[mt][reg] = scale[co]; shr[mt][reg] = shift[co];
    }
  float v[2][4][4];
#pragma unroll
  for (int tile = 0; tile < 2; ++tile)
#pragma unroll
    for (int mt = 0; mt < 4; ++mt)
#pragma unroll
      for (int reg = 0; reg < 4; ++reg) v[tile][mt][reg] = 0.f;

#pragma unroll 1
  for (int t = 0; t < 8; ++t) {
    int tb = t * 128 + b;
    const float* xb = x + tb * 3072;
    __syncthreads();
    for (int i = tid; i < 648; i += 256) {
      int ci = i / 216, r1 = i - ci * 216;
      int rr = r1 / 36, c = r1 - rr * 36;
      int gy = y0 - 1 + rr, gx = c - 1;
      xs[i] = ((unsigned)gy < 32u && (unsigned)gx < 32u) ? xb[(ci * 32 + gy) * 32 + gx] : 0.f;
    }
    __syncthreads();
    f32x4 acc[2][4];
#pragma unroll
    for (int tile = 0; tile < 2; ++tile)
#pragma unroll
      for (int mt = 0; mt < 4; ++mt) acc[tile][mt] = (f32x4){0.f, 0.f, 0.f, 0.f};
#pragma unroll
    for (int tile = 0; tile < 2; ++tile) {
      short8 Bh = (short8){0,0,0,0,0,0,0,0};
      short8 Bl = (short8){0,0,0,0,0,0,0,0};
      short8 Bll = (short8){0,0,0,0,0,0,0,0};
#pragma unroll
      for (int j = 0; j < 8; ++j) {
        float xv = vld[j] ? xs[cb[j] + tile * 16] : 0.f;
        unsigned short h = f2bf(xv);
        float r = xv - bf2f(h);
        unsigned short l = f2bf(r);
        float r2 = r - bf2f(l);
        Bh[j] = (short)h; Bl[j] = (short)l; Bll[j] = (short)f2bf(r2);
      }
#pragma unroll
      for (int mt = 0; mt < 4; ++mt) {
        f32x4 a = acc[tile][mt];
        a = __builtin_amdgcn_mfma_f32_16x16x32_bf16(A[0][mt], Bh, a, 0, 0, 0);
        a = __builtin_amdgcn_mfma_f32_16x16x32_bf16(A[1][mt], Bh, a, 0, 0, 0);
        a = __builtin_amdgcn_mfma_f32_16x16x32_bf16(A[2][mt], Bh, a, 0, 0, 0);
        a = __builtin_amdgcn_mfma_f32_16x16x32_bf16(A[0][mt], Bl, a, 0, 0, 0);
        a = __builtin_amdgcn_mfma_f32_16x16x32_bf16(A[1][mt], Bl, a, 0, 0, 0);
        a = __builtin_amdgcn_mfma_f32_16x16x32_bf16(A[2][mt], Bl, a, 0, 0, 0);
        a = __builtin_amdgcn_mfma_f32_16x16x32_bf16(A[0][mt], Bll, a, 0, 0, 0);
        a = __builtin_amdgcn_mfma_f32_16x16x32_bf16(A[1][mt], Bll, a, 0, 0, 0);
        acc[tile][mt] = a;
      }
    }
#pragma unroll
    for (int mt = 0; mt < 4; ++mt)
#pragma unroll
      for (int rp = 0; rp < 2; ++rp) {
        float hp[2][2];
#pragma unroll
        for (int tile = 0; tile < 2; ++tile)
#pragma unroll
          for (int e = 0; e < 2; ++e) {
            int reg = rp * 2 + e;
            float xv = fmaf(acc[tile][mt][reg], scr[mt][reg], shr[mt][reg]);
            float spk;
            LIF_STEP(v[tile][mt][reg], xv, spk);
            hp[tile][e] = spk + __shfl_xor(spk, 1);
          }
        int tw = xl & 1;
        float h0 = tw ? hp[1][0] : hp[0][0];
        float h1 = tw ? hp[1][1] : hp[0][1];
        unsigned u = (unsigned)f2bf(h0) | ((unsigned)f2bf(h1) << 16);
        int pp = tw * 8 + (xl >> 1);
        *(unsigned*)&shout[(wave * 16 + pp) * 72 + mt * 16 + q * 4 + rp * 2] = u;
      }
    __syncthreads();
    {
      int cg = tid >> 5, py_l = (tid >> 4) & 1, px = tid & 15;
      uint4 ua = *(const uint4*)&shout[((2 * py_l) * 16 + px) * 72 + cg * 8];
      uint4 ub = *(const uint4*)&shout[((2 * py_l + 1) * 16 + px) * 72 + cg * 8];
      const unsigned* pa = (const unsigned*)&ua;
      const unsigned* pb = (const unsigned*)&ub;
      unsigned o[4];
#pragma unroll
      for (int e = 0; e < 4; ++e) {
        float a0 = bf2f((unsigned short)(pa[e] & 0xffffu)), a1 = bf2f((unsigned short)(pa[e] >> 16));
        float b0 = bf2f((unsigned short)(pb[e] & 0xffffu)), b1 = bf2f((unsigned short)(pb[e] >> 16));
        o[e] = (unsigned)f2bf(0.25f * (a0 + b0)) | ((unsigned)f2bf(0.25f * (a1 + b1)) << 16);
      }
      int py = yq * 2 + py_l;
      *(uint4*)(pool1 + (size_t)tb * 16384 + cg * 2048 + (py * 16 + px) * 8) =
          make_uint4(o[0], o[1], o[2], o[3]);
    }
  }
}

// ---- conv2 helpers: A-frag load + one kc MFMA step ----
__device__ __forceinline__ void c2_load_a(const unsigned short* __restrict__ A2, int kc,
                                          int m0, int xl, int q, short8 (&a)[2][3]) {
#pragma unroll
  for (int mt = 0; mt < 2; ++mt) {
    int aoff = ((kc * 128 + m0 + mt * 16 + xl) * 4 + q) * 8;
    a[mt][0] = *(const short8*)(A2 + aoff);
    a[mt][1] = *(const short8*)(A2 + 73728 + aoff);
    a[mt][2] = *(const short8*)(A2 + 147456 + aoff);
  }
}
__device__ __forceinline__ void c2_step(const unsigned short* __restrict__ simg, int kc,
                                        int xl, int q, short8 (&a)[2][3], f32x4 (&acc)[2][4]) {
  int tap = kc >> 1;
  int dy = tap / 3, dx = tap - dy * 3;
  int cgq = (kc & 1) * 4 + q;
#pragma unroll
  for (int yl = 0; yl < 4; ++yl) {
    int baddr = (((yl + dy) * 8 + cgq) * 18 + (xl + dx)) * 8;
    short8 bb = *(const short8*)(simg + baddr);
#pragma unroll
    for (int mt = 0; mt < 2; ++mt) {
      acc[mt][yl] = __builtin_amdgcn_mfma_f32_16x16x32_bf16(a[mt][0], bb, acc[mt][yl], 0, 0, 0);
      acc[mt][yl] = __builtin_amdgcn_mfma_f32_16x16x32_bf16(a[mt][1], bb, acc[mt][yl], 0, 0, 0);
      acc[mt][yl] = __builtin_amdgcn_mfma_f32_16x16x32_bf16(a[mt][2], bb, acc[mt][yl], 0, 0, 0);
    }
  }
}

// ---- conv2 (MFMA, single pass): stats + fp32 preact store. R10: unroll-2 rotation. ----
__global__ __launch_bounds__(256, 2) void conv2_store_mfma(const unsigned short* __restrict__ pool1,
    const unsigned short* __restrict__ A2, float* __restrict__ preact, float* __restrict__ s2p) {
  int bx = blockIdx.x;
  int tb = bx >> 2, q4 = bx & 3;
  int sp = bx & 63;
  __shared__ unsigned short simg[6 * 8 * 18 * 8];
  int tid = threadIdx.x;
  const unsigned* src = (const unsigned*)(pool1 + (size_t)tb * 16384);
  unsigned* dstw = (unsigned*)simg;
  for (int i = tid; i < 3456; i += 256) {
    int cp = i & 3, rest = i >> 2;
    int jj = rest / 18, xx = rest - jj * 18;
    int cg = jj & 7, row_l = jj >> 3;
    int yi = q4 * 4 - 1 + row_l, gx = xx - 1;
    unsigned val = 0u;
    if ((unsigned)yi < 16u && (unsigned)gx < 16u)
      val = src[cg * 1024 + yi * 64 + gx * 4 + cp];
    dstw[i] = val;
  }
  __syncthreads();

  int wave = tid >> 6, lane = tid & 63;
  int xl = lane & 15, q = lane >> 4;
  int m0 = wave * 32;
  f32x4 acc[2][4];
#pragma unroll
  for (int mt = 0; mt < 2; ++mt)
#pragma unroll
    for (int yl = 0; yl < 4; ++yl) acc[mt][yl] = (f32x4){0.f, 0.f, 0.f, 0.f};

  short8 aA[2][3], aB[2][3];
  c2_load_a(A2, 0, m0, xl, q, aA);
#pragma unroll 1
  for (int kc = 0; kc < 18; kc += 2) {
    c2_load_a(A2, kc + 1, m0, xl, q, aB);       // kc+1 <= 17 always
    c2_step(simg, kc, xl, q, aA, acc);
    if (kc + 2 < 18) c2_load_a(A2, kc + 2, m0, xl, q, aA);
    c2_step(simg, kc + 1, xl, q, aB, acc);
  }

  float* pre = preact + (size_t)tb * 32768;
#pragma unroll
  for (int mt = 0; mt < 2; ++mt)
#pragma unroll
    for (int reg = 0; reg < 4; ++reg) {
      int co = m0 + mt * 16 + q * 4 + reg;
      float s1 = 0.f, s2 = 0.f;
#pragma unroll
      for (int yl = 0; yl < 4; ++yl) {
        float val = acc[mt][yl][reg];
        int row = q4 * 4 + yl;
        pre[(row * 128 + co) * 16 + xl] = val;
        s1 += val; s2 = fmaf(val, val, s2);
      }
#pragma unroll
      for (int off = 1; off < 16; off <<= 1) {
        s1 += __shfl_xor(s1, off); s2 += __shfl_xor(s2, off);
      }
      if (xl == 0) {
        atomicAdd(&s2p[sp * 256 + co], s1);
        atomicAdd(&s2p[sp * 256 + 128 + co], s2);
      }
    }
}

// ---- BN2 + LIF + pool over stored preact. R10: block = (b, pool-row); grid 1024. ----
__global__ __launch_bounds__(256) void bn2_lif_pool(const float* __restrict__ pre,
    const float* __restrict__ scale, const float* __restrict__ shift,
    unsigned short* __restrict__ pool2) {
  int b = blockIdx.x >> 3, py = blockIdx.x & 7;
  int tid = threadIdx.x;
  int co = tid >> 1, half = tid & 1;
  __shared__ unsigned short shout[8 * 136];
  float sc = scale[co], sh = shift[co];
  float v[4][4];   // [p][window elem]
#pragma unroll
  for (int p = 0; p < 4; ++p)
#pragma unroll
    for (int e = 0; e < 4; ++e) v[p][e] = 0.f;

#pragma unroll 1
  for (int t = 0; t < 8; ++t) {
    const float* base = pre + ((size_t)((t * 128 + b) * 16 + 2 * py)) * 2048 + co * 16 + half * 8;
    __syncthreads();
    float4 r0a = *(const float4*)(base);
    float4 r0b = *(const float4*)(base + 4);
    float4 r1a = *(const float4*)(base + 2048);
    float4 r1b = *(const float4*)(base + 2048 + 4);
    float p00[4] = {r0a.x, r0a.z, r0b.x, r0b.z};
    float p01[4] = {r0a.y, r0a.w, r0b.y, r0b.w};
    float p10[4] = {r1a.x, r1a.z, r1b.x, r1b.z};
    float p11[4] = {r1a.y, r1a.w, r1b.y, r1b.w};
#pragma unroll
    for (int p = 0; p < 4; ++p) {
      float s00, s01, s10, s11, xv;
      xv = fmaf(p00[p], sc, sh); LIF_STEP(v[p][0], xv, s00);
      xv = fmaf(p01[p], sc, sh); LIF_STEP(v[p][1], xv, s01);
      xv = fmaf(p10[p], sc, sh); LIF_STEP(v[p][2], xv, s10);
      xv = fmaf(p11[p], sc, sh); LIF_STEP(v[p][3], xv, s11);
      shout[(half * 4 + p) * 136 + co] = f2bf(0.25f * (s00 + s01 + s10 + s11));
    }
    __syncthreads();
    {
      int s_l = tid >> 5, ci4 = (tid & 31) * 4;
      uint2 vv = *(const uint2*)&shout[s_l * 136 + ci4];
      *(uint2*)(pool2 + ((size_t)(t * 128 + b) * 64 + py * 8 + s_l) * 128 + ci4) = vv;
    }
  }
}

// ---- fc1 (MFMA): partial[kb][o 256][tb 1024], split-K=16, no atomics. (validated) ----
__global__ __launch_bounds__(256, 2) void fc1_mfma(const unsigned short* __restrict__ pool2,
    const unsigned short* __restrict__ B1, float* __restrict__ partial) {
  int bx = blockIdx.x;
  int t_o = bx & 1, tbt = (bx >> 1) & 15, kb = bx >> 5;
  int tid = threadIdx.x, wave = tid >> 6, lane = tid & 63;
  int xl = lane & 15, q = lane >> 4;
  int m0 = t_o * 128 + wave * 32;
  int n0 = tbt * 64;
  __shared__ unsigned short sB[64 * 42];
  f32x4 acc[2][4];
#pragma unroll
  for (int mt = 0; mt < 2; ++mt)
#pragma unroll
    for (int nt = 0; nt < 4; ++nt) acc[mt][nt] = (f32x4){0.f, 0.f, 0.f, 0.f};

#pragma unroll 1
  for (int kc0 = 0; kc0 < 16; ++kc0) {
    int kc = kb * 16 + kc0;
    __syncthreads();
    {
      int tb_l = tid >> 2, kq = tid & 3;
      uint4 vv = *(const uint4*)(pool2 + (size_t)(n0 + tb_l) * 8192 + kc * 32 + kq * 8);
      *(uint4*)(sB + tb_l * 42 + kq * 8) = vv;
    }
    __syncthreads();
    short8 a[2][3];
#pragma unroll
    for (int mt = 0; mt < 2; ++mt) {
      int aoff = ((kc * 256 + m0 + mt * 16 + xl) * 4 + q) * 8;
      a[mt][0] = *(const short8*)(B1 + aoff);
      a[mt][1] = *(const short8*)(B1 + 2097152 + aoff);
      a[mt][2] = *(const short8*)(B1 + 4194304 + aoff);
    }
#pragma unroll
    for (int nt = 0; nt < 4; ++nt) {
      short8 bb = *(const short8*)(sB + (nt * 16 + xl) * 42 + q * 8);
#pragma unroll
      for (int mt = 0; mt < 2; ++mt) {
        acc[mt][nt] = __builtin_amdgcn_mfma_f32_16x16x32_bf16(a[mt][0], bb, acc[mt][nt], 0, 0, 0);
        acc[mt][nt] = __builtin_amdgcn_mfma_f32_16x16x32_bf16(a[mt][1], bb, acc[mt][nt], 0, 0, 0);
        acc[mt][nt] = __builtin_amdgcn_mfma_f32_16x16x32_bf16(a[mt][2], bb, acc[mt][nt], 0, 0, 0);
      }
    }
  }
#pragma unroll
  for (int mt = 0; mt < 2; ++mt)
#pragma unroll
    for (int nt = 0; nt < 4; ++nt)
#pragma unroll
      for (int reg = 0; reg < 4; ++reg) {
        int o = m0 + mt * 16 + q * 4 + reg;
        partial[((size_t)kb * 256 + o) * 1024 + n0 + nt * 16 + xl] = acc[mt][nt][reg];
      }
}

// ---- reduce partials + LIF -> fc1 spikes [t][b][o]. ----
__global__ __launch_bounds__(256) void reduce_lif(const float* __restrict__ partial, float* __restrict__ fs) {
  int idx = blockIdx.x * 256 + threadIdx.x;
  int o = idx >> 7, b = idx & 127;
  float v = 0.f;
#pragma unroll 1
  for (int t = 0; t < 8; ++t) {
    float xv = 0.f;
#pragma unroll
    for (int kb = 0; kb < 16; ++kb)
      xv += partial[((size_t)kb * 256 + o) * 1024 + t * 128 + b];
    float s;
    LIF_STEP(v, xv, s);
    fs[t * 32768 + b * 256 + o] = s;
  }
}

__global__ __launch_bounds__(256) void fc2_kernel(const float* __restrict__ fs, const float* __restrict__ w,
                                                  const float* __restrict__ bias, float* __restrict__ outp) {
  int tb = blockIdx.x;
  __shared__ float sv[256];
  int tid = threadIdx.x;
  sv[tid] = fs[tb * 256 + tid];
  __syncthreads();
  if (tid < 10) {
    float a = bias[tid];
    const float* wr = w + tid * 256;
#pragma unroll 8
    for (int o = 0; o < 256; ++o) a = fmaf(sv[o], wr[o], a);
    outp[tb * 10 + tid] = a;
  }
}

extern "C" void kernel_launch(void* const* d_in, const int* in_sizes, int n_in,
                              void* d_out, int out_size, void* d_ws, size_t ws_size,
                              hipStream_t stream) {
  (void)in_sizes; (void)n_in; (void)out_size; (void)ws_size;
  const float* x_seq   = (const float*)d_in[0];
  const float* conv1_w = (const float*)d_in[1];
  const float* bn1_g   = (const float*)d_in[2];
  const float* bn1_b   = (const float*)d_in[3];
  const float* conv2_w = (const float*)d_in[4];
  const float* bn2_g   = (const float*)d_in[5];
  const float* bn2_b   = (const float*)d_in[6];
  const float* fc1_w   = (const float*)d_in[7];
  const float* fc2_w   = (const float*)d_in[8];
  const float* fc2_b   = (const float*)d_in[9];
  float* out = (float*)d_out;
  float* ws  = (float*)d_ws;

  unsigned short* pool1 = (unsigned short*)(ws + OFF_POOL1);
  float* fc1_part = ws + OFF_POOL1;              // pool1 dead after conv2_store
  unsigned short* pool2 = (unsigned short*)(ws + OFF_POOL2);
  float* preact  = ws + OFF_PRE;
  float* fc1_s   = ws + OFF_FC1S;
  unsigned short* A2 = (unsigned short*)(ws + OFF_A2);
  unsigned short* B1 = (unsigned short*)(ws + OFF_B1);
  unsigned short* A1 = (unsigned short*)(ws + OFF_A1);
  float* st      = ws + OFF_STATS;
  float* s1p    = st;            // [64 sp][2][64]
  float* s2p    = st + 8192;     // [64 sp][2][128]
  float* bn1_sc = st + 24576;  float* bn1_sh = st + 24640;
  float* bn2_sc = st + 24704;  float* bn2_sh = st + 24832;

  zero_kernel<<<96, 256, 0, stream>>>(st, ZERO_STATS);
  prep_w1<<<8, 256, 0, stream>>>(conv1_w, A1);
  prep_w2<<<288, 256, 0, stream>>>(conv2_w, A2);
  prep_b1<<<384, 256, 0, stream>>>(fc1_w, B1);
  conv1_pass1_mfma<<<1024, 256, 0, stream>>>(x_seq, A1, s1p);
  finalize_bn1<<<1, 64, 0, stream>>>(s1p, bn1_g, bn1_b, bn1_sc, bn1_sh, 1.0f / 1048576.0f);
  conv1_fused_mfma<<<1024, 256, 0, stream>>>(x_seq, A1, bn1_sc, bn1_sh, pool1);
  conv2_store_mfma<<<4096, 256, 0, stream>>>(pool1, A2, preact, s2p);
  finalize_bn2<<<1, 128, 0, stream>>>(s2p, bn2_g, bn2_b, bn2_sc, bn2_sh, 1.0f / 262144.0f);
  bn2_lif_pool<<<1024, 256, 0, stream>>>(preact, bn2_sc, bn2_sh, pool2);
  fc1_mfma<<<512, 256, 0, stream>>>(pool2, B1, fc1_part);
  reduce_lif<<<128, 256, 0, stream>>>(fc1_part, fc1_s);
  fc2_kernel<<<1024, 256, 0, stream>>>(fc1_s, fc2_w, fc2_b, out);
}

// Round 11
// 362.735 us; speedup vs baseline: 1.7778x; 1.1097x over previous
//
#include <hip/hip_runtime.h>

// SNN forward — all three heavy ops (conv1, conv2, fc1) on MFMA bf16.
// R11: conv2_store re-tiled to 8 rows/block (grid 2048) — halves per-output
//      A-frag L2 traffic (1.8 GB -> 0.9 GB) and barrier count;
//      fc1_mfma stages 2 kc per barrier pair (32 -> 16 syncs).

#define LIF_STEP(vv, xx, ss) do { \
    vv = fmaf((xx) - vv, 0.5f, vv); \
    ss = (vv >= 1.0f) ? 1.0f : 0.0f; \
    vv = (vv >= 1.0f) ? 0.0f : vv; \
  } while (0)

typedef __attribute__((ext_vector_type(8))) short short8;
typedef __attribute__((ext_vector_type(4))) float f32x4;

__device__ __forceinline__ float bf2f(unsigned short u) {
  return __uint_as_float(((unsigned)u) << 16);
}
__device__ __forceinline__ unsigned short f2bf(float f) {
  return (unsigned short)(__float_as_uint(f) >> 16);  // truncation split
}

// ---- workspace layout (float-slot offsets) ----
// pool1 bf16 [1024 tb][8 cg][16 py][16 px][8 ci_l] = 16,777,216 u16 (8,388,608 f)
//   (reused AFTER conv2_store as fc1 partials f32 [16 kb][256 o][1024 tb])
// pool2 bf16 [1024 tb][64 s][128 ci] = 8,388,608 u16 (4,194,304 f)
// preact f32 [1024 tb][16 row][128 co][16 col] = 33,554,432 f
#define OFF_POOL1   0u
#define OFF_POOL2   8388608u
#define OFF_PRE     12582912u
#define OFF_STATS   46137344u   // f32 24,960
#define OFF_FC1S    46162304u   // f32 262,144
#define OFF_A2      46424448u   // bf16 3x[18 kc][128 co][4 q][8 j]
#define OFF_B1      46535040u   // bf16 3x[256 kc][256 o][4 q][8 j]
#define OFF_A1      49680768u   // bf16 3x[64 co][32 k]
// total 49,683,840 floats = 198.7 MB
// stats sublayout: s1p[64 sp][2][64] | s2p[64 sp][2][128] | bn1_sc/sh(64) bn2_sc/sh(128)
#define ZERO_STATS 24576u

__global__ __launch_bounds__(256) void zero_kernel(float* __restrict__ p, unsigned n) {
  unsigned i = blockIdx.x * 256u + threadIdx.x;
  if (i < n) p[i] = 0.0f;
}

// conv1_w [64 co][3 ci][3 ky][3 kx] -> A1[sv][co][k], k = tap*3+ci, k>=27 zero
__global__ __launch_bounds__(256) void prep_w1(const float* __restrict__ w, unsigned short* __restrict__ A1) {
  int i = blockIdx.x * 256 + threadIdx.x;
  if (i >= 2048) return;
  int co = i >> 5, k = i & 31;
  float wv = 0.f;
  if (k < 27) {
    int tap = k / 3, ci = k - tap * 3;
    wv = w[co * 27 + ci * 9 + tap];
  }
  unsigned short hi = f2bf(wv);
  float rem = wv - bf2f(hi);
  unsigned short lo = f2bf(rem);
  float rem2 = rem - bf2f(lo);
  A1[i] = hi;
  A1[2048 + i] = lo;
  A1[4096 + i] = f2bf(rem2);
}

// conv2_w -> 3-way bf16 split in MFMA A-frag order (validated)
__global__ __launch_bounds__(256) void prep_w2(const float* __restrict__ w, unsigned short* __restrict__ A2) {
  int i = blockIdx.x * 256 + threadIdx.x;
  if (i >= 73728) return;
  int co = i / 576, r = i - co * 576;
  int ci = r / 9, t9 = r - ci * 9;
  int k = t9 * 64 + ci;
  int kc = k >> 5, q = (k >> 3) & 3, j = k & 7;
  int off = ((kc * 128 + co) * 4 + q) * 8 + j;
  float wv = w[i];
  unsigned short hi = f2bf(wv);
  float rem = wv - bf2f(hi);
  unsigned short lo = f2bf(rem);
  float rem2 = rem - bf2f(lo);
  A2[off] = hi;
  A2[73728 + off] = lo;
  A2[147456 + off] = f2bf(rem2);
}

// fc1_w -> 3-way split via LDS transpose; one sv per block (grid 384)
__global__ __launch_bounds__(256) void prep_b1(const float* __restrict__ w, unsigned short* __restrict__ B1) {
  __shared__ unsigned short sh[2][8192];
  int blk = blockIdx.x;        // 384 = sv*128 + opair
  int sv = blk >> 7, opair = blk & 127;
  int tid = threadIdx.x;
  for (int o_l = 0; o_l < 2; ++o_l) {
    for (int it = 0; it < 32; ++it) {
      int korig = tid + 256 * it;
      float wv = w[(size_t)(opair * 2 + o_l) * 8192 + korig];
      unsigned short hi = f2bf(wv);
      float rem = wv - bf2f(hi);
      unsigned short lo = f2bf(rem);
      unsigned short pc = (sv == 0) ? hi : (sv == 1) ? lo : f2bf(rem - bf2f(lo));
      int k = (korig & 63) * 128 + (korig >> 6);
      sh[o_l][k] = pc;
    }
  }
  __syncthreads();
  unsigned short* outp = B1 + (size_t)sv * 2097152;
  for (int it = 0; it < 64; ++it) {
    int idx = tid + 256 * it;
    int kc = idx >> 6, r = idx & 63;
    int o_l = r >> 5, m = r & 31;
    outp[kc * 8192 + opair * 64 + r] = sh[o_l][kc * 32 + m];
  }
}

// layer-1 finalize: reduce 64-way spread partials [sp][2][64]
__global__ void finalize_bn1(const float* __restrict__ s1p,
                             const float* __restrict__ g, const float* __restrict__ b,
                             float* __restrict__ scale, float* __restrict__ shift, float inv_n) {
  int c = threadIdx.x;
  float s1 = 0.f, s2 = 0.f;
#pragma unroll 8
  for (int sp = 0; sp < 64; ++sp) {
    s1 += s1p[sp * 128 + c];
    s2 += s1p[sp * 128 + 64 + c];
  }
  float mean = s1 * inv_n;
  float var = fmaxf(s2 * inv_n - mean * mean, 0.0f);
  float rstd = rsqrtf(var + 1e-5f);
  float sc = g[c] * rstd;
  scale[c] = sc;
  shift[c] = fmaf(-mean, sc, b[c]);
}

// layer-2 finalize: reduce 64-way spread partials [sp][2][128]
__global__ void finalize_bn2(const float* __restrict__ s2p,
                             const float* __restrict__ g, const float* __restrict__ b,
                             float* __restrict__ scale, float* __restrict__ shift, float inv_n) {
  int c = threadIdx.x;
  float s1 = 0.f, s2 = 0.f;
#pragma unroll 8
  for (int sp = 0; sp < 64; ++sp) {
    s1 += s2p[sp * 256 + c];
    s2 += s2p[sp * 256 + 128 + c];
  }
  float mean = s1 * inv_n;
  float var = fmaxf(s2 * inv_n - mean * mean, 0.0f);
  float rstd = rsqrtf(var + 1e-5f);
  float sc = g[c] * rstd;
  scale[c] = sc;
  shift[c] = fmaf(-mean, sc, b[c]);
}

// ---- conv1 pass 1 (MFMA im2col): stats only. (validated R9) ----
__global__ __launch_bounds__(256) void conv1_pass1_mfma(const float* __restrict__ x,
    const unsigned short* __restrict__ A1, float* __restrict__ s1p) {
  int b = blockIdx.x >> 3, yq = blockIdx.x & 7;
  int y0 = yq * 4;
  int sp = blockIdx.x & 63;
  int tid = threadIdx.x, wave = tid >> 6, lane = tid & 63;
  int xl = lane & 15, q = lane >> 4;
  __shared__ float xs[648];
  short8 A[3][4];
#pragma unroll
  for (int mt = 0; mt < 4; ++mt) {
    int aoff = (mt * 16 + xl) * 32 + q * 8;
    A[0][mt] = *(const short8*)(A1 + aoff);
    A[1][mt] = *(const short8*)(A1 + 2048 + aoff);
    A[2][mt] = *(const short8*)(A1 + 4096 + aoff);
  }
  int cb[8]; bool vld[8];
#pragma unroll
  for (int j = 0; j < 8; ++j) {
    int k = q * 8 + j;
    int tap = k / 3, ci = k - tap * 3;
    int dy = tap / 3, dx = tap - dy * 3;
    vld[j] = (k < 27);
    cb[j] = ci * 216 + (wave + dy) * 36 + dx + xl;
  }
  float s1[4][4], s2[4][4];
#pragma unroll
  for (int mt = 0; mt < 4; ++mt)
#pragma unroll
    for (int reg = 0; reg < 4; ++reg) { s1[mt][reg] = 0.f; s2[mt][reg] = 0.f; }

#pragma unroll 1
  for (int t = 0; t < 8; ++t) {
    int tb = t * 128 + b;
    const float* xb = x + tb * 3072;
    __syncthreads();
    for (int i = tid; i < 648; i += 256) {
      int ci = i / 216, r1 = i - ci * 216;
      int rr = r1 / 36, c = r1 - rr * 36;
      int gy = y0 - 1 + rr, gx = c - 1;
      xs[i] = ((unsigned)gy < 32u && (unsigned)gx < 32u) ? xb[(ci * 32 + gy) * 32 + gx] : 0.f;
    }
    __syncthreads();
    f32x4 acc[2][4];
#pragma unroll
    for (int tile = 0; tile < 2; ++tile)
#pragma unroll
      for (int mt = 0; mt < 4; ++mt) acc[tile][mt] = (f32x4){0.f, 0.f, 0.f, 0.f};
#pragma unroll
    for (int tile = 0; tile < 2; ++tile) {
      short8 Bh = (short8){0,0,0,0,0,0,0,0};
      short8 Bl = (short8){0,0,0,0,0,0,0,0};
      short8 Bll = (short8){0,0,0,0,0,0,0,0};
#pragma unroll
      for (int j = 0; j < 8; ++j) {
        float xv = vld[j] ? xs[cb[j] + tile * 16] : 0.f;
        unsigned short h = f2bf(xv);
        float r = xv - bf2f(h);
        unsigned short l = f2bf(r);
        float r2 = r - bf2f(l);
        Bh[j] = (short)h; Bl[j] = (short)l; Bll[j] = (short)f2bf(r2);
      }
#pragma unroll
      for (int mt = 0; mt < 4; ++mt) {
        f32x4 a = acc[tile][mt];
        a = __builtin_amdgcn_mfma_f32_16x16x32_bf16(A[0][mt], Bh, a, 0, 0, 0);
        a = __builtin_amdgcn_mfma_f32_16x16x32_bf16(A[1][mt], Bh, a, 0, 0, 0);
        a = __builtin_amdgcn_mfma_f32_16x16x32_bf16(A[2][mt], Bh, a, 0, 0, 0);
        a = __builtin_amdgcn_mfma_f32_16x16x32_bf16(A[0][mt], Bl, a, 0, 0, 0);
        a = __builtin_amdgcn_mfma_f32_16x16x32_bf16(A[1][mt], Bl, a, 0, 0, 0);
        a = __builtin_amdgcn_mfma_f32_16x16x32_bf16(A[2][mt], Bl, a, 0, 0, 0);
        a = __builtin_amdgcn_mfma_f32_16x16x32_bf16(A[0][mt], Bll, a, 0, 0, 0);
        a = __builtin_amdgcn_mfma_f32_16x16x32_bf16(A[1][mt], Bll, a, 0, 0, 0);
        acc[tile][mt] = a;
      }
    }
#pragma unroll
    for (int tile = 0; tile < 2; ++tile)
#pragma unroll
      for (int mt = 0; mt < 4; ++mt)
#pragma unroll
        for (int reg = 0; reg < 4; ++reg) {
          float val = acc[tile][mt][reg];
          s1[mt][reg] += val; s2[mt][reg] = fmaf(val, val, s2[mt][reg]);
        }
  }
#pragma unroll
  for (int mt = 0; mt < 4; ++mt)
#pragma unroll
    for (int reg = 0; reg < 4; ++reg) {
      float a1 = s1[mt][reg], a2 = s2[mt][reg];
#pragma unroll
      for (int off = 1; off < 16; off <<= 1) { a1 += __shfl_xor(a1, off); a2 += __shfl_xor(a2, off); }
      if (xl == 0) {
        int co = mt * 16 + q * 4 + reg;
        atomicAdd(&s1p[sp * 128 + co], a1);
        atomicAdd(&s1p[sp * 128 + 64 + co], a2);
      }
    }
}

// ---- conv1 pass 2 (MFMA im2col): fused conv+BN+LIF+pool -> pool1. (validated R9) ----
__global__ __launch_bounds__(256) void conv1_fused_mfma(const float* __restrict__ x,
    const unsigned short* __restrict__ A1, const float* __restrict__ scale,
    const float* __restrict__ shift, unsigned short* __restrict__ pool1) {
  int b = blockIdx.x >> 3, yq = blockIdx.x & 7;
  int y0 = yq * 4;
  int tid = threadIdx.x, wave = tid >> 6, lane = tid & 63;
  int xl = lane & 15, q = lane >> 4;
  __shared__ float xs[648];
  __shared__ unsigned short shout[4 * 16 * 72];
  short8 A[3][4];
#pragma unroll
  for (int mt = 0; mt < 4; ++mt) {
    int aoff = (mt * 16 + xl) * 32 + q * 8;
    A[0][mt] = *(const short8*)(A1 + aoff);
    A[1][mt] = *(const short8*)(A1 + 2048 + aoff);
    A[2][mt] = *(const short8*)(A1 + 4096 + aoff);
  }
  int cb[8]; bool vld[8];
#pragma unroll
  for (int j = 0; j < 8; ++j) {
    int k = q * 8 + j;
    int tap = k / 3, ci = k - tap * 3;
    int dy = tap / 3, dx = tap - dy * 3;
    vld[j] = (k < 27);
    cb[j] = ci * 216 + (wave + dy) * 36 + dx + xl;
  }
  float scr[4][4], shr[4][4];
#pragma unroll
  for (int mt = 0; mt < 4; ++mt)
#pragma unroll
    for (int reg = 0; reg < 4; ++reg) {
      int co = mt * 16 + q * 4 + reg;
      scr[mt][reg] = scale[co]; shr[mt][reg] = shift[co];
    }
  float v[2][4][4];
#pragma unroll
  for (int tile = 0; tile < 2; ++tile)
#pragma unroll
    for (int mt = 0; mt < 4; ++mt)
#pragma unroll
      for (int reg = 0; reg < 4; ++reg) v[tile][mt][reg] = 0.f;

#pragma unroll 1
  for (int t = 0; t < 8; ++t) {
    int tb = t * 128 + b;
    const float* xb = x + tb * 3072;
    __syncthreads();
    for (int i = tid; i < 648; i += 256) {
      int ci = i / 216, r1 = i - ci * 216;
      int rr = r1 / 36, c = r1 - rr * 36;
      int gy = y0 - 1 + rr, gx = c - 1;
      xs[i] = ((unsigned)gy < 32u && (unsigned)gx < 32u) ? xb[(ci * 32 + gy) * 32 + gx] : 0.f;
    }
    __syncthreads();
    f32x4 acc[2][4];
#pragma unroll
    for (int tile = 0; tile < 2; ++tile)
#pragma unroll
      for (int mt = 0; mt < 4; ++mt) acc[tile][mt] = (f32x4){0.f, 0.f, 0.f, 0.f};
#pragma unroll
    for (int tile = 0; tile < 2; ++tile) {
      short8 Bh = (short8){0,0,0,0,0,0,0,0};
      short8 Bl = (short8){0,0,0,0,0,0,0,0};
      short8 Bll = (short8){0,0,0,0,0,0,0,0};
#pragma unroll
      for (int j = 0; j < 8; ++j) {
        float xv = vld[j] ? xs[cb[j] + tile * 16] : 0.f;
        unsigned short h = f2bf(xv);
        float r = xv - bf2f(h);
        unsigned short l = f2bf(r);
        float r2 = r - bf2f(l);
        Bh[j] = (short)h; Bl[j] = (short)l; Bll[j] = (short)f2bf(r2);
      }
#pragma unroll
      for (int mt = 0; mt < 4; ++mt) {
        f32x4 a = acc[tile][mt];
        a = __builtin_amdgcn_mfma_f32_16x16x32_bf16(A[0][mt], Bh, a, 0, 0, 0);
        a = __builtin_amdgcn_mfma_f32_16x16x32_bf16(A[1][mt], Bh, a, 0, 0, 0);
        a = __builtin_amdgcn_mfma_f32_16x16x32_bf16(A[2][mt], Bh, a, 0, 0, 0);
        a = __builtin_amdgcn_mfma_f32_16x16x32_bf16(A[0][mt], Bl, a, 0, 0, 0);
        a = __builtin_amdgcn_mfma_f32_16x16x32_bf16(A[1][mt], Bl, a, 0, 0, 0);
        a = __builtin_amdgcn_mfma_f32_16x16x32_bf16(A[2][mt], Bl, a, 0, 0, 0);
        a = __builtin_amdgcn_mfma_f32_16x16x32_bf16(A[0][mt], Bll, a, 0, 0, 0);
        a = __builtin_amdgcn_mfma_f32_16x16x32_bf16(A[1][mt], Bll, a, 0, 0, 0);
        acc[tile][mt] = a;
      }
    }
#pragma unroll
    for (int mt = 0; mt < 4; ++mt)
#pragma unroll
      for (int rp = 0; rp < 2; ++rp) {
        float hp[2][2];
#pragma unroll
        for (int tile = 0; tile < 2; ++tile)
#pragma unroll
          for (int e = 0; e < 2; ++e) {
            int reg = rp * 2 + e;
            float xv = fmaf(acc[tile][mt][reg], scr[mt][reg], shr[mt][reg]);
            float spk;
            LIF_STEP(v[tile][mt][reg], xv, spk);
            hp[tile][e] = spk + __shfl_xor(spk, 1);
          }
        int tw = xl & 1;
        float h0 = tw ? hp[1][0] : hp[0][0];
        float h1 = tw ? hp[1][1] : hp[0][1];
        unsigned u = (unsigned)f2bf(h0) | ((unsigned)f2bf(h1) << 16);
        int pp = tw * 8 + (xl >> 1);
        *(unsigned*)&shout[(wave * 16 + pp) * 72 + mt * 16 + q * 4 + rp * 2] = u;
      }
    __syncthreads();
    {
      int cg = tid >> 5, py_l = (tid >> 4) & 1, px = tid & 15;
      uint4 ua = *(const uint4*)&shout[((2 * py_l) * 16 + px) * 72 + cg * 8];
      uint4 ub = *(const uint4*)&shout[((2 * py_l + 1) * 16 + px) * 72 + cg * 8];
      const unsigned* pa = (const unsigned*)&ua;
      const unsigned* pb = (const unsigned*)&ub;
      unsigned o[4];
#pragma unroll
      for (int e = 0; e < 4; ++e) {
        float a0 = bf2f((unsigned short)(pa[e] & 0xffffu)), a1 = bf2f((unsigned short)(pa[e] >> 16));
        float b0 = bf2f((unsigned short)(pb[e] & 0xffffu)), b1 = bf2f((unsigned short)(pb[e] >> 16));
        o[e] = (unsigned)f2bf(0.25f * (a0 + b0)) | ((unsigned)f2bf(0.25f * (a1 + b1)) << 16);
      }
      int py = yq * 2 + py_l;
      *(uint4*)(pool1 + (size_t)tb * 16384 + cg * 2048 + (py * 16 + px) * 8) =
          make_uint4(o[0], o[1], o[2], o[3]);
    }
  }
}

// ---- conv2 helpers ----
__device__ __forceinline__ void c2_load_a(const unsigned short* __restrict__ A2, int kc,
                                          int m0, int xl, int q, short8 (&a)[2][3]) {
#pragma unroll
  for (int mt = 0; mt < 2; ++mt) {
    int aoff = ((kc * 128 + m0 + mt * 16 + xl) * 4 + q) * 8;
    a[mt][0] = *(const short8*)(A2 + aoff);
    a[mt][1] = *(const short8*)(A2 + 73728 + aoff);
    a[mt][2] = *(const short8*)(A2 + 147456 + aoff);
  }
}
__device__ __forceinline__ void c2_step8(const unsigned short* __restrict__ simg, int kc,
                                         int xl, int q, short8 (&a)[2][3], f32x4 (&acc)[2][8]) {
  int tap = kc >> 1;
  int dy = tap / 3, dx = tap - dy * 3;
  int cgq = (kc & 1) * 4 + q;
#pragma unroll
  for (int yl = 0; yl < 8; ++yl) {
    int baddr = (((yl + dy) * 8 + cgq) * 18 + (xl + dx)) * 8;
    short8 bb = *(const short8*)(simg + baddr);
#pragma unroll
    for (int mt = 0; mt < 2; ++mt) {
      acc[mt][yl] = __builtin_amdgcn_mfma_f32_16x16x32_bf16(a[mt][0], bb, acc[mt][yl], 0, 0, 0);
      acc[mt][yl] = __builtin_amdgcn_mfma_f32_16x16x32_bf16(a[mt][1], bb, acc[mt][yl], 0, 0, 0);
      acc[mt][yl] = __builtin_amdgcn_mfma_f32_16x16x32_bf16(a[mt][2], bb, acc[mt][yl], 0, 0, 0);
    }
  }
}

// ---- conv2 (MFMA, single pass): stats + fp32 preact store. R11: 8 rows/block. ----
__global__ __launch_bounds__(256, 2) void conv2_store_mfma(const unsigned short* __restrict__ pool1,
    const unsigned short* __restrict__ A2, float* __restrict__ preact, float* __restrict__ s2p) {
  int bx = blockIdx.x;
  int tb = bx >> 1, half = bx & 1;
  int sp = bx & 63;
  __shared__ unsigned short simg[10 * 8 * 18 * 8];   // 23,040 B : rows half*8-1 .. half*8+8
  int tid = threadIdx.x;
  const unsigned* src = (const unsigned*)(pool1 + (size_t)tb * 16384);
  unsigned* dstw = (unsigned*)simg;
  for (int i = tid; i < 5760; i += 256) {
    int cp = i & 3, rest = i >> 2;
    int jj = rest / 18, xx = rest - jj * 18;
    int cg = jj & 7, row_l = jj >> 3;
    int yi = half * 8 - 1 + row_l, gx = xx - 1;
    unsigned val = 0u;
    if ((unsigned)yi < 16u && (unsigned)gx < 16u)
      val = src[cg * 1024 + yi * 64 + gx * 4 + cp];
    dstw[i] = val;
  }
  __syncthreads();

  int wave = tid >> 6, lane = tid & 63;
  int xl = lane & 15, q = lane >> 4;
  int m0 = wave * 32;
  f32x4 acc[2][8];
#pragma unroll
  for (int mt = 0; mt < 2; ++mt)
#pragma unroll
    for (int yl = 0; yl < 8; ++yl) acc[mt][yl] = (f32x4){0.f, 0.f, 0.f, 0.f};

  short8 aA[2][3], aB[2][3];
  c2_load_a(A2, 0, m0, xl, q, aA);
#pragma unroll 1
  for (int kc = 0; kc < 18; kc += 2) {
    c2_load_a(A2, kc + 1, m0, xl, q, aB);
    c2_step8(simg, kc, xl, q, aA, acc);
    if (kc + 2 < 18) c2_load_a(A2, kc + 2, m0, xl, q, aA);
    c2_step8(simg, kc + 1, xl, q, aB, acc);
  }

  float* pre = preact + (size_t)tb * 32768;
#pragma unroll
  for (int mt = 0; mt < 2; ++mt)
#pragma unroll
    for (int reg = 0; reg < 4; ++reg) {
      int co = m0 + mt * 16 + q * 4 + reg;
      float s1 = 0.f, s2 = 0.f;
#pragma unroll
      for (int yl = 0; yl < 8; ++yl) {
        float val = acc[mt][yl][reg];
        int row = half * 8 + yl;
        pre[(row * 128 + co) * 16 + xl] = val;
        s1 += val; s2 = fmaf(val, val, s2);
      }
#pragma unroll
      for (int off = 1; off < 16; off <<= 1) {
        s1 += __shfl_xor(s1, off); s2 += __shfl_xor(s2, off);
      }
      if (xl == 0) {
        atomicAdd(&s2p[sp * 256 + co], s1);
        atomicAdd(&s2p[sp * 256 + 128 + co], s2);
      }
    }
}

// ---- BN2 + LIF + pool over stored preact. (validated R10) ----
__global__ __launch_bounds__(256) void bn2_lif_pool(const float* __restrict__ pre,
    const float* __restrict__ scale, const float* __restrict__ shift,
    unsigned short* __restrict__ pool2) {
  int b = blockIdx.x >> 3, py = blockIdx.x & 7;
  int tid = threadIdx.x;
  int co = tid >> 1, half = tid & 1;
  __shared__ unsigned short shout[8 * 136];
  float sc = scale[co], sh = shift[co];
  float v[4][4];
#pragma unroll
  for (int p = 0; p < 4; ++p)
#pragma unroll
    for (int e = 0; e < 4; ++e) v[p][e] = 0.f;

#pragma unroll 1
  for (int t = 0; t < 8; ++t) {
    const float* base = pre + ((size_t)((t * 128 + b) * 16 + 2 * py)) * 2048 + co * 16 + half * 8;
    __syncthreads();
    float4 r0a = *(const float4*)(base);
    float4 r0b = *(const float4*)(base + 4);
    float4 r1a = *(const float4*)(base + 2048);
    float4 r1b = *(const float4*)(base + 2048 + 4);
    float p00[4] = {r0a.x, r0a.z, r0b.x, r0b.z};
    float p01[4] = {r0a.y, r0a.w, r0b.y, r0b.w};
    float p10[4] = {r1a.x, r1a.z, r1b.x, r1b.z};
    float p11[4] = {r1a.y, r1a.w, r1b.y, r1b.w};
#pragma unroll
    for (int p = 0; p < 4; ++p) {
      float s00, s01, s10, s11, xv;
      xv = fmaf(p00[p], sc, sh); LIF_STEP(v[p][0], xv, s00);
      xv = fmaf(p01[p], sc, sh); LIF_STEP(v[p][1], xv, s01);
      xv = fmaf(p10[p], sc, sh); LIF_STEP(v[p][2], xv, s10);
      xv = fmaf(p11[p], sc, sh); LIF_STEP(v[p][3], xv, s11);
      shout[(half * 4 + p) * 136 + co] = f2bf(0.25f * (s00 + s01 + s10 + s11));
    }
    __syncthreads();
    {
      int s_l = tid >> 5, ci4 = (tid & 31) * 4;
      uint2 vv = *(const uint2*)&shout[s_l * 136 + ci4];
      *(uint2*)(pool2 + ((size_t)(t * 128 + b) * 64 + py * 8 + s_l) * 128 + ci4) = vv;
    }
  }
}

// ---- fc1 (MFMA): partial[kb][o 256][tb 1024], split-K=16. R11: 2 kc per barrier pair. ----
__global__ __launch_bounds__(256, 2) void fc1_mfma(const unsigned short* __restrict__ pool2,
    const unsigned short* __restrict__ B1, float* __restrict__ partial) {
  int bx = blockIdx.x;
  int t_o = bx & 1, tbt = (bx >> 1) & 15, kb = bx >> 5;
  int tid = threadIdx.x, wave = tid >> 6, lane = tid & 63;
  int xl = lane & 15, q = lane >> 4;
  int m0 = t_o * 128 + wave * 32;
  int n0 = tbt * 64;
  __shared__ unsigned short sB[2][64 * 42];
  f32x4 acc[2][4];
#pragma unroll
  for (int mt = 0; mt < 2; ++mt)
#pragma unroll
    for (int nt = 0; nt < 4; ++nt) acc[mt][nt] = (f32x4){0.f, 0.f, 0.f, 0.f};

#pragma unroll 1
  for (int kc0 = 0; kc0 < 16; kc0 += 2) {
    int kc = kb * 16 + kc0;
    __syncthreads();
    {
      int tb_l = tid >> 2, kq = tid & 3;
      const unsigned short* srcp = pool2 + (size_t)(n0 + tb_l) * 8192 + kc * 32 + kq * 8;
      uint4 v0 = *(const uint4*)(srcp);
      uint4 v1 = *(const uint4*)(srcp + 32);
      *(uint4*)(sB[0] + tb_l * 42 + kq * 8) = v0;
      *(uint4*)(sB[1] + tb_l * 42 + kq * 8) = v1;
    }
    __syncthreads();
#pragma unroll
    for (int sub = 0; sub < 2; ++sub) {
      int kcs = kc + sub;
      short8 a[2][3];
#pragma unroll
      for (int mt = 0; mt < 2; ++mt) {
        int aoff = ((kcs * 256 + m0 + mt * 16 + xl) * 4 + q) * 8;
        a[mt][0] = *(const short8*)(B1 + aoff);
        a[mt][1] = *(const short8*)(B1 + 2097152 + aoff);
        a[mt][2] = *(const short8*)(B1 + 4194304 + aoff);
      }
#pragma unroll
      for (int nt = 0; nt < 4; ++nt) {
        short8 bb = *(const short8*)(sB[sub] + (nt * 16 + xl) * 42 + q * 8);
#pragma unroll
        for (int mt = 0; mt < 2; ++mt) {
          acc[mt][nt] = __builtin_amdgcn_mfma_f32_16x16x32_bf16(a[mt][0], bb, acc[mt][nt], 0, 0, 0);
          acc[mt][nt] = __builtin_amdgcn_mfma_f32_16x16x32_bf16(a[mt][1], bb, acc[mt][nt], 0, 0, 0);
          acc[mt][nt] = __builtin_amdgcn_mfma_f32_16x16x32_bf16(a[mt][2], bb, acc[mt][nt], 0, 0, 0);
        }
      }
    }
  }
#pragma unroll
  for (int mt = 0; mt < 2; ++mt)
#pragma unroll
    for (int nt = 0; nt < 4; ++nt)
#pragma unroll
      for (int reg = 0; reg < 4; ++reg) {
        int o = m0 + mt * 16 + q * 4 + reg;
        partial[((size_t)kb * 256 + o) * 1024 + n0 + nt * 16 + xl] = acc[mt][nt][reg];
      }
}

// ---- reduce partials + LIF -> fc1 spikes [t][b][o]. ----
__global__ __launch_bounds__(256) void reduce_lif(const float* __restrict__ partial, float* __restrict__ fs) {
  int idx = blockIdx.x * 256 + threadIdx.x;
  int o = idx >> 7, b = idx & 127;
  float v = 0.f;
#pragma unroll 1
  for (int t = 0; t < 8; ++t) {
    float xv = 0.f;
#pragma unroll
    for (int kb = 0; kb < 16; ++kb)
      xv += partial[((size_t)kb * 256 + o) * 1024 + t * 128 + b];
    float s;
    LIF_STEP(v, xv, s);
    fs[t * 32768 + b * 256 + o] = s;
  }
}

__global__ __launch_bounds__(256) void fc2_kernel(const float* __restrict__ fs, const float* __restrict__ w,
                                                  const float* __restrict__ bias, float* __restrict__ outp) {
  int tb = blockIdx.x;
  __shared__ float sv[256];
  int tid = threadIdx.x;
  sv[tid] = fs[tb * 256 + tid];
  __syncthreads();
  if (tid < 10) {
    float a = bias[tid];
    const float* wr = w + tid * 256;
#pragma unroll 8
    for (int o = 0; o < 256; ++o) a = fmaf(sv[o], wr[o], a);
    outp[tb * 10 + tid] = a;
  }
}

extern "C" void kernel_launch(void* const* d_in, const int* in_sizes, int n_in,
                              void* d_out, int out_size, void* d_ws, size_t ws_size,
                              hipStream_t stream) {
  (void)in_sizes; (void)n_in; (void)out_size; (void)ws_size;
  const float* x_seq   = (const float*)d_in[0];
  const float* conv1_w = (const float*)d_in[1];
  const float* bn1_g   = (const float*)d_in[2];
  const float* bn1_b   = (const float*)d_in[3];
  const float* conv2_w = (const float*)d_in[4];
  const float* bn2_g   = (const float*)d_in[5];
  const float* bn2_b   = (const float*)d_in[6];
  const float* fc1_w   = (const float*)d_in[7];
  const float* fc2_w   = (const float*)d_in[8];
  const float* fc2_b   = (const float*)d_in[9];
  float* out = (float*)d_out;
  float* ws  = (float*)d_ws;

  unsigned short* pool1 = (unsigned short*)(ws + OFF_POOL1);
  float* fc1_part = ws + OFF_POOL1;              // pool1 dead after conv2_store
  unsigned short* pool2 = (unsigned short*)(ws + OFF_POOL2);
  float* preact  = ws + OFF_PRE;
  float* fc1_s   = ws + OFF_FC1S;
  unsigned short* A2 = (unsigned short*)(ws + OFF_A2);
  unsigned short* B1 = (unsigned short*)(ws + OFF_B1);
  unsigned short* A1 = (unsigned short*)(ws + OFF_A1);
  float* st      = ws + OFF_STATS;
  float* s1p    = st;            // [64 sp][2][64]
  float* s2p    = st + 8192;     // [64 sp][2][128]
  float* bn1_sc = st + 24576;  float* bn1_sh = st + 24640;
  float* bn2_sc = st + 24704;  float* bn2_sh = st + 24832;

  zero_kernel<<<96, 256, 0, stream>>>(st, ZERO_STATS);
  prep_w1<<<8, 256, 0, stream>>>(conv1_w, A1);
  prep_w2<<<288, 256, 0, stream>>>(conv2_w, A2);
  prep_b1<<<384, 256, 0, stream>>>(fc1_w, B1);
  conv1_pass1_mfma<<<1024, 256, 0, stream>>>(x_seq, A1, s1p);
  finalize_bn1<<<1, 64, 0, stream>>>(s1p, bn1_g, bn1_b, bn1_sc, bn1_sh, 1.0f / 1048576.0f);
  conv1_fused_mfma<<<1024, 256, 0, stream>>>(x_seq, A1, bn1_sc, bn1_sh, pool1);
  conv2_store_mfma<<<2048, 256, 0, stream>>>(pool1, A2, preact, s2p);
  finalize_bn2<<<1, 128, 0, stream>>>(s2p, bn2_g, bn2_b, bn2_sc, bn2_sh, 1.0f / 262144.0f);
  bn2_lif_pool<<<1024, 256, 0, stream>>>(preact, bn2_sc, bn2_sh, pool2);
  fc1_mfma<<<512, 256, 0, stream>>>(pool2, B1, fc1_part);
  reduce_lif<<<128, 256, 0, stream>>>(fc1_part, fc1_s);
  fc2_kernel<<<1024, 256, 0, stream>>>(fc1_s, fc2_w, fc2_b, out);
}